// Round 7
// baseline (290.446 us; speedup 1.0000x reference)
//
#include <hip/hip_runtime.h>
#include <hip/hip_bf16.h>

typedef __attribute__((ext_vector_type(8))) short short8;
typedef __attribute__((ext_vector_type(4))) float f32x4;

#define INF38 1e38f
#define SCALE 0.04419417382415922f   // 1/sqrt(512)

__device__ __forceinline__ float bfu(unsigned short u){
  return __uint_as_float(((unsigned int)u) << 16);
}
__device__ __forceinline__ unsigned short f2b(float x){
  unsigned int b = __float_as_uint(x);
  return (unsigned short)((b + 0x7fffu + ((b>>16)&1u)) >> 16);   // RNE
}
__device__ __forceinline__ float ldf(const void* p, long i, int isbf){
  if (isbf) return bfu(((const unsigned short*)p)[i]);
  return ((const float*)p)[i];
}
__device__ __forceinline__ void stf(void* p, long i, float x, int isbf){
  if (isbf) ((unsigned short*)p)[i] = f2b(x);
  else ((float*)p)[i] = x;
}
// 8 contiguous elems -> 8 bf16 packed in a uint4 (direct copy if already bf16)
__device__ __forceinline__ uint4 load8bf(const void* p, long idx, int isbf){
  if (isbf) return *(const uint4*)((const unsigned short*)p + idx);
  const float* f = (const float*)p + idx;
  float4 a = *(const float4*)f, b = *(const float4*)(f+4);
  uint4 r;
  r.x = (unsigned)f2b(a.x) | ((unsigned)f2b(a.y)<<16);
  r.y = (unsigned)f2b(a.z) | ((unsigned)f2b(a.w)<<16);
  r.z = (unsigned)f2b(b.x) | ((unsigned)f2b(b.y)<<16);
  r.w = (unsigned)f2b(b.z) | ((unsigned)f2b(b.w)<<16);
  return r;
}

// ---------------- dtype probe (bf16 vs f32 input buffers) ----------------
__global__ void probe_dtype(const unsigned short* q, int* flag){
  const int t = threadIdx.x;
  int good = 0;
  for (int i = t; i < 2048; i += 256){
    float ax = fabsf(bfu(q[i]));
    good += (ax > 1e-3f && ax < 16.f) ? 1 : 0;
  }
  __shared__ int sh[256];
  sh[t] = good; __syncthreads();
  for (int st = 128; st > 0; st >>= 1){ if (t < st) sh[t] += sh[t+st]; __syncthreads(); }
  if (t == 0) *flag = (sh[0] >= 1536) ? 1 : 0;
}

// ---------------- weight transpose: wt[n][k] = W[k][n], bf16 ----------------
__global__ __launch_bounds__(256) void prep_w(
    const void* Wq, const void* Wk, const void* Wv, const void* Wo,
    unsigned short* wt, const int* flagp)
{
  const int isbf = *flagp;
  const int m = blockIdx.z;
  const void* W = (m==0)?Wq:(m==1)?Wk:(m==2)?Wv:Wo;
  unsigned short* dst = wt + (long)m*262144;
  __shared__ unsigned short tile[64][72];
  const int t = threadIdx.x;
  const int n0 = blockIdx.x*64, k0 = blockIdx.y*64;
  {
    int r = t>>2, c0 = (t&3)*16;
    uint4 u0 = load8bf(W, (long)(k0+r)*512 + n0 + c0, isbf);
    uint4 u1 = load8bf(W, (long)(k0+r)*512 + n0 + c0 + 8, isbf);
    unsigned short* us0 = (unsigned short*)&u0;
    unsigned short* us1 = (unsigned short*)&u1;
    #pragma unroll
    for (int i=0;i<8;++i) tile[c0+i][r] = us0[i];
    #pragma unroll
    for (int i=0;i<8;++i) tile[c0+8+i][r] = us1[i];
  }
  __syncthreads();
  {
    int n = t>>2, ks = (t&3)*16;
    *(uint4*)(dst + (long)(n0+n)*512 + k0 + ks)     = *(uint4*)&tile[n][ks];
    *(uint4*)(dst + (long)(n0+n)*512 + k0 + ks + 8) = *(uint4*)&tile[n][ks+8];
  }
}

// ---------------- QKV projection (bf16 MFMA) ----------------
// q,k natural [token][512] bf16; v per-head-transposed [(b*8+h)*64+d][1024] bf16.
__global__ __launch_bounds__(256) void proj_mfma(
    const void* queries, const void* keys, const unsigned short* wt,
    const void* bq, const void* bk, const void* bv,
    unsigned short* q_bf, unsigned short* k_bf, unsigned short* vt_bf,
    const int* flagp)
{
  const int isbf = *flagp;
  const int mat = blockIdx.z;
  const void* A = (mat==0)? queries : keys;
  const unsigned short* Wt = wt + (long)mat*262144;
  const void* bias = (mat==0)?bq:(mat==1)?bk:bv;
  const int row0 = blockIdx.y*128, col0 = blockIdx.x*128;
  __shared__ unsigned short As[128][40];
  __shared__ unsigned short Ws[128][40];
  const int t = threadIdx.x;
  const int lane = t & 63, wid = t >> 6;
  const int ln = lane & 15, quad = lane >> 4;
  const int wy = wid >> 1, wx = wid & 1;
  f32x4 acc[4][4];
  #pragma unroll
  for (int i=0;i<4;++i){
    #pragma unroll
    for (int j=0;j<4;++j) acc[i][j] = (f32x4){0.f,0.f,0.f,0.f};
  }
  const int sr = t>>1, sk0 = (t&1)*16;
  for (int k0=0;k0<512;k0+=32){
    __syncthreads();
    {
      uint4 u0 = load8bf(A, (long)(row0+sr)*512 + k0 + sk0, isbf);
      uint4 u1 = load8bf(A, (long)(row0+sr)*512 + k0 + sk0 + 8, isbf);
      *(uint4*)&As[sr][sk0]   = u0;
      *(uint4*)&As[sr][sk0+8] = u1;
      uint4 w0 = *(const uint4*)(Wt + (long)(col0+sr)*512 + k0 + sk0);
      uint4 w1 = *(const uint4*)(Wt + (long)(col0+sr)*512 + k0 + sk0 + 8);
      *(uint4*)&Ws[sr][sk0]   = w0;
      *(uint4*)&Ws[sr][sk0+8] = w1;
    }
    __syncthreads();
    short8 a[4], b[4];
    #pragma unroll
    for (int mt=0;mt<4;++mt) a[mt] = *(const short8*)&As[wy*64+mt*16+ln][quad*8];
    #pragma unroll
    for (int nt=0;nt<4;++nt) b[nt] = *(const short8*)&Ws[wx*64+nt*16+ln][quad*8];
    #pragma unroll
    for (int mt=0;mt<4;++mt){
      #pragma unroll
      for (int nt=0;nt<4;++nt)
        acc[mt][nt] = __builtin_amdgcn_mfma_f32_16x16x32_bf16(a[mt], b[nt], acc[mt][nt], 0,0,0);
    }
  }
  float bias_v[4];
  #pragma unroll
  for (int nt=0;nt<4;++nt) bias_v[nt] = ldf(bias, col0 + wx*64 + nt*16 + ln, isbf);
  if (mat < 2){
    unsigned short* dst = (mat==0)? q_bf : k_bf;
    #pragma unroll
    for (int mt=0;mt<4;++mt){
      int row = row0 + wy*64 + mt*16 + quad*4;
      #pragma unroll
      for (int nt=0;nt<4;++nt){
        int col = col0 + wx*64 + nt*16 + ln;
        #pragma unroll
        for (int r=0;r<4;++r)
          dst[(long)(row+r)*512 + col] = f2b(acc[mt][nt][r] + bias_v[nt]);
      }
    }
  } else {
    #pragma unroll
    for (int mt=0;mt<4;++mt){
      int row = row0 + wy*64 + mt*16 + quad*4;   // token base, 4-aligned
      int bb = row >> 10, sk = row & 1023;
      #pragma unroll
      for (int nt=0;nt<4;++nt){
        int col = col0 + wx*64 + nt*16 + ln;
        int h = col >> 6, dd = col & 63;
        uint2 pk2; unsigned short* pp = (unsigned short*)&pk2;
        #pragma unroll
        for (int r=0;r<4;++r) pp[r] = f2b(acc[mt][nt][r] + bias_v[nt]);
        *(uint2*)(vt_bf + (((long)((bb*8+h)*64+dd)) << 10) + sk) = pk2;
      }
    }
  }
}

// ---------------- flash attention (bf16 MFMA) ----------------
// Block = one (b,h,64-q-tile). 4 waves, each a 16-q strip. P LDS round-trip.
__global__ __launch_bounds__(256) void attn_mfma(
    const unsigned short* q_bf, const unsigned short* k_bf, const unsigned short* vt_bf,
    const void* pres_q, const void* pres_k, float* o1, const int* flagp)
{
  const int isbf = *flagp;
  const int b = blockIdx.z, h = blockIdx.y, q0 = blockIdx.x*64;
  const int t = threadIdx.x;
  const int lane = t&63, wid = t>>6, ln = lane&15, quad = lane>>4;
  __shared__ unsigned short Qs[64][72];   // [q][d]
  __shared__ unsigned short Ks[64][72];   // [key][d]
  __shared__ unsigned short Vt[64][72];   // [d][key]
  __shared__ unsigned short Ps[64][72];   // [q][key] bf16 probs
  __shared__ float pq_s[64], pk_s[64];
  {
    int tok = t>>2, ds = (t&3)*16;
    const unsigned short* src = q_bf + (long)(b*1024 + q0 + tok)*512 + h*64 + ds;
    *(uint4*)&Qs[tok][ds]   = *(const uint4*)src;
    *(uint4*)&Qs[tok][ds+8] = *(const uint4*)(src+8);
  }
  if (t < 64) pq_s[t] = ldf(pres_q, (long)b*1024 + q0 + t, isbf);
  f32x4 oacc[4];
  #pragma unroll
  for (int dt=0;dt<4;++dt) oacc[dt] = (f32x4){0.f,0.f,0.f,0.f};
  float m_st[4], l_st[4];
  #pragma unroll
  for (int r=0;r<4;++r){ m_st[r] = -INFINITY; l_st[r] = 0.f; }

  for (int k0=0;k0<1024;k0+=64){
    __syncthreads();                      // prev PV done with Vt/Ps
    {
      int tok = t>>2, ds = (t&3)*16;
      const unsigned short* sk = k_bf + (long)(b*1024 + k0 + tok)*512 + h*64 + ds;
      *(uint4*)&Ks[tok][ds]   = *(const uint4*)sk;
      *(uint4*)&Ks[tok][ds+8] = *(const uint4*)(sk+8);
      const unsigned short* sv = vt_bf + (((long)((b*8+h)*64 + tok)) << 10) + k0 + ds;
      *(uint4*)&Vt[tok][ds]   = *(const uint4*)sv;
      *(uint4*)&Vt[tok][ds+8] = *(const uint4*)(sv+8);
    }
    if (t < 64) pk_s[t] = ldf(pres_k, (long)b*1024 + k0 + t, isbf);
    __syncthreads();
    // S = Q K^T : 16q x 64k per wave
    f32x4 s[4];
    #pragma unroll
    for (int kt=0;kt<4;++kt) s[kt] = (f32x4){0.f,0.f,0.f,0.f};
    short8 aq0 = *(const short8*)&Qs[wid*16+ln][quad*8];
    short8 aq1 = *(const short8*)&Qs[wid*16+ln][32+quad*8];
    #pragma unroll
    for (int kt=0;kt<4;++kt){
      short8 kb0 = *(const short8*)&Ks[kt*16+ln][quad*8];
      short8 kb1 = *(const short8*)&Ks[kt*16+ln][32+quad*8];
      s[kt] = __builtin_amdgcn_mfma_f32_16x16x32_bf16(aq0, kb0, s[kt], 0,0,0);
      s[kt] = __builtin_amdgcn_mfma_f32_16x16x32_bf16(aq1, kb1, s[kt], 0,0,0);
    }
    // mask + online softmax (rows = quad*4+r, cols across ln & kt)
    float pk4[4];
    #pragma unroll
    for (int kt=0;kt<4;++kt) pk4[kt] = pk_s[kt*16+ln];
    float alpha[4];
    #pragma unroll
    for (int r=0;r<4;++r){
      float pq = pq_s[wid*16 + quad*4 + r];
      float sv[4]; float mloc = -INFINITY;
      #pragma unroll
      for (int kt=0;kt<4;++kt){
        float x = s[kt][r]*SCALE;
        x = pq*x - (1.f-pq)*INF38;
        x = pk4[kt]*x - (1.f-pk4[kt])*INF38;
        sv[kt] = x; mloc = fmaxf(mloc, x);
      }
      #pragma unroll
      for (int msk=1; msk<16; msk<<=1) mloc = fmaxf(mloc, __shfl_xor(mloc, msk));
      float mn = fmaxf(m_st[r], mloc);
      float lloc = 0.f;
      #pragma unroll
      for (int kt=0;kt<4;++kt){ sv[kt] = __expf(sv[kt]-mn); lloc += sv[kt]; }
      #pragma unroll
      for (int msk=1; msk<16; msk<<=1) lloc += __shfl_xor(lloc, msk);
      alpha[r] = __expf(m_st[r]-mn);
      l_st[r] = l_st[r]*alpha[r] + lloc;
      m_st[r] = mn;
      #pragma unroll
      for (int kt=0;kt<4;++kt) Ps[wid*16+quad*4+r][kt*16+ln] = f2b(sv[kt]);
    }
    #pragma unroll
    for (int dt=0;dt<4;++dt){
      #pragma unroll
      for (int r=0;r<4;++r) oacc[dt][r] *= alpha[r];
    }
    __syncthreads();                      // Ps visible
    // O += P V : 16q x 64d per wave
    short8 ap0 = *(const short8*)&Ps[wid*16+ln][quad*8];
    short8 ap1 = *(const short8*)&Ps[wid*16+ln][32+quad*8];
    #pragma unroll
    for (int dt=0;dt<4;++dt){
      short8 vb0 = *(const short8*)&Vt[dt*16+ln][quad*8];
      short8 vb1 = *(const short8*)&Vt[dt*16+ln][32+quad*8];
      oacc[dt] = __builtin_amdgcn_mfma_f32_16x16x32_bf16(ap0, vb0, oacc[dt], 0,0,0);
      oacc[dt] = __builtin_amdgcn_mfma_f32_16x16x32_bf16(ap1, vb1, oacc[dt], 0,0,0);
    }
  }
  // epilogue: o = qh + (P V)/l  — l reduced once over the 16-lane crews
  #pragma unroll
  for (int r=0;r<4;++r){
    float inv = 1.f / l_st[r];
    int ql = wid*16 + quad*4 + r;
    long base = (long)(b*1024 + q0 + ql)*512 + h*64;
    #pragma unroll
    for (int dt=0;dt<4;++dt)
      o1[base + dt*16 + ln] = bfu(Qs[ql][dt*16+ln]) + oacc[dt][r]*inv;
  }
}

// ---------------- layernorm (wave per row), bf16 out ----------------
// mode 0: write bf16 to internal buffer; mode 1: flagged store to d_out
__global__ __launch_bounds__(256) void ln_kernel(
    const float* in, void* outp, int mode,
    const void* g, const void* bvec, const int* flagp)
{
  const int isbf = *flagp;
  const int row = blockIdx.x*4 + (threadIdx.x >> 6);
  const int lane = threadIdx.x & 63;
  const float* x = in + (long)row*512 + lane*8;
  float v[8];
  *(float4*)&v[0] = *(const float4*)x;
  *(float4*)&v[4] = *(const float4*)(x + 4);
  float sum = 0.f;
  #pragma unroll
  for (int c=0;c<8;++c) sum += v[c];
  #pragma unroll
  for (int msk=1; msk<64; msk<<=1) sum += __shfl_xor(sum, msk);
  float mu = sum * (1.f/512.f);
  float var = 0.f;
  #pragma unroll
  for (int c=0;c<8;++c){ v[c] -= mu; var += v[c]*v[c]; }
  #pragma unroll
  for (int msk=1; msk<64; msk<<=1) var += __shfl_xor(var, msk);
  float rs = rsqrtf(var*(1.f/512.f) + 1e-5f);
  #pragma unroll
  for (int c=0;c<8;++c){
    int col = lane*8 + c;
    float y = v[c]*rs*ldf(g, col, isbf) + ldf(bvec, col, isbf);
    long idx = (long)row*512 + col;
    if (mode) stf(outp, idx, y, isbf);
    else ((unsigned short*)outp)[idx] = f2b(y);
  }
}

// ---------------- out projection: u = t + relu(t @ Wo + bo) ----------------
__global__ __launch_bounds__(256) void out_mfma(
    const unsigned short* t_bf, const unsigned short* Wt, const void* bo,
    float* o1, const int* flagp)
{
  const int isbf = *flagp;
  const int row0 = blockIdx.y*128, col0 = blockIdx.x*128;
  __shared__ unsigned short As[128][40];
  __shared__ unsigned short Ws[128][40];
  const int t = threadIdx.x;
  const int lane = t & 63, wid = t >> 6;
  const int ln = lane & 15, quad = lane >> 4;
  const int wy = wid >> 1, wx = wid & 1;
  f32x4 acc[4][4];
  #pragma unroll
  for (int i=0;i<4;++i){
    #pragma unroll
    for (int j=0;j<4;++j) acc[i][j] = (f32x4){0.f,0.f,0.f,0.f};
  }
  const int sr = t>>1, sk0 = (t&1)*16;
  for (int k0=0;k0<512;k0+=32){
    __syncthreads();
    {
      *(uint4*)&As[sr][sk0]   = *(const uint4*)(t_bf + (long)(row0+sr)*512 + k0 + sk0);
      *(uint4*)&As[sr][sk0+8] = *(const uint4*)(t_bf + (long)(row0+sr)*512 + k0 + sk0 + 8);
      *(uint4*)&Ws[sr][sk0]   = *(const uint4*)(Wt + (long)(col0+sr)*512 + k0 + sk0);
      *(uint4*)&Ws[sr][sk0+8] = *(const uint4*)(Wt + (long)(col0+sr)*512 + k0 + sk0 + 8);
    }
    __syncthreads();
    short8 a[4], b[4];
    #pragma unroll
    for (int mt=0;mt<4;++mt) a[mt] = *(const short8*)&As[wy*64+mt*16+ln][quad*8];
    #pragma unroll
    for (int nt=0;nt<4;++nt) b[nt] = *(const short8*)&Ws[wx*64+nt*16+ln][quad*8];
    #pragma unroll
    for (int mt=0;mt<4;++mt){
      #pragma unroll
      for (int nt=0;nt<4;++nt)
        acc[mt][nt] = __builtin_amdgcn_mfma_f32_16x16x32_bf16(a[mt], b[nt], acc[mt][nt], 0,0,0);
    }
  }
  float bias_v[4];
  #pragma unroll
  for (int nt=0;nt<4;++nt) bias_v[nt] = ldf(bo, col0 + wx*64 + nt*16 + ln, isbf);
  #pragma unroll
  for (int mt=0;mt<4;++mt){
    int row = row0 + wy*64 + mt*16 + quad*4;
    #pragma unroll
    for (int nt=0;nt<4;++nt){
      int col = col0 + wx*64 + nt*16 + ln;
      #pragma unroll
      for (int r=0;r<4;++r){
        long idx = (long)(row+r)*512 + col;
        float u = acc[mt][nt][r] + bias_v[nt];
        u = fmaxf(u, 0.f);
        o1[idx] = bfu(t_bf[idx]) + u;
      }
    }
  }
}

extern "C" void kernel_launch(void* const* d_in, const int* in_sizes, int n_in,
                              void* d_out, int out_size, void* d_ws, size_t ws_size,
                              hipStream_t stream)
{
  // ws (bytes): q_bf 8.4M | k_bf 8.4M | vt_bf 8.4M | t_bf 8.4M | wt 2M | o1 16.8M | flag
  unsigned short* q_bf  = (unsigned short*)d_ws;
  unsigned short* k_bf  = q_bf  + 8192l*512;
  unsigned short* vt_bf = k_bf  + 8192l*512;
  unsigned short* t_bf  = vt_bf + 8192l*512;
  unsigned short* wt    = t_bf  + 8192l*512;
  float* o1   = (float*)(wt + 4l*512*512);
  int*   flag = (int*)(o1 + 8192l*512);

  hipLaunchKernelGGL(probe_dtype, dim3(1), dim3(256), 0, stream,
                     (const unsigned short*)d_in[0], flag);
  hipLaunchKernelGGL(prep_w, dim3(8,8,4), dim3(256), 0, stream,
                     d_in[5], d_in[7], d_in[9], d_in[11], wt, flag);
  hipLaunchKernelGGL(proj_mfma, dim3(4,64,3), dim3(256), 0, stream,
                     d_in[0], d_in[1], wt, d_in[6], d_in[8], d_in[10],
                     q_bf, k_bf, vt_bf, flag);
  hipLaunchKernelGGL(attn_mfma, dim3(16,8,8), dim3(256), 0, stream,
                     q_bf, k_bf, vt_bf, d_in[2], d_in[3], o1, flag);
  hipLaunchKernelGGL(ln_kernel, dim3(2048), dim3(256), 0, stream,
                     o1, (void*)t_bf, 0, d_in[13], d_in[14], flag);
  hipLaunchKernelGGL(out_mfma, dim3(4,64), dim3(256), 0, stream,
                     t_bf, wt + 3l*512*512, d_in[12], o1, flag);
  hipLaunchKernelGGL(ln_kernel, dim3(2048), dim3(256), 0, stream,
                     o1, d_out, 1, d_in[15], d_in[16], flag);
}

// Round 8
// 221.457 us; speedup vs baseline: 1.3115x; 1.3115x over previous
//
#include <hip/hip_runtime.h>

typedef __attribute__((ext_vector_type(8))) short short8;
typedef __attribute__((ext_vector_type(4))) float f32x4;

#define SCALE2 0.06375871571f   // (1/sqrt(512)) * log2(e)
#define C1     674.4237f        // 43 / SCALE2

__device__ __forceinline__ float bfu(unsigned short u){
  return __uint_as_float(((unsigned int)u) << 16);
}
__device__ __forceinline__ unsigned short f2b(float x){   // RNE
  unsigned int b = __float_as_uint(x);
  return (unsigned short)((b + 0x7fffu + ((b>>16)&1u)) >> 16);
}
// 8 contiguous f32 -> 8 bf16 packed in a uint4
__device__ __forceinline__ uint4 pack8(const float* f){
  float4 a = *(const float4*)f, b = *(const float4*)(f+4);
  uint4 r;
  r.x = (unsigned)f2b(a.x) | ((unsigned)f2b(a.y)<<16);
  r.y = (unsigned)f2b(a.z) | ((unsigned)f2b(a.w)<<16);
  r.z = (unsigned)f2b(b.x) | ((unsigned)f2b(b.y)<<16);
  r.w = (unsigned)f2b(b.z) | ((unsigned)f2b(b.w)<<16);
  return r;
}

// ---------------- weight transpose: wt[n][k] = W[k][n] (f32 -> bf16) ----------------
__global__ __launch_bounds__(256) void prep_w(
    const float* Wq, const float* Wk, const float* Wv, const float* Wo,
    unsigned short* wt)
{
  const int m = blockIdx.z;
  const float* W = (m==0)?Wq:(m==1)?Wk:(m==2)?Wv:Wo;
  unsigned short* dst = wt + (long)m*262144;
  __shared__ unsigned short tile[64][72];
  const int t = threadIdx.x;
  const int n0 = blockIdx.x*64, k0 = blockIdx.y*64;
  {
    int r = t>>2, c0 = (t&3)*16;
    uint4 u0 = pack8(W + (long)(k0+r)*512 + n0 + c0);
    uint4 u1 = pack8(W + (long)(k0+r)*512 + n0 + c0 + 8);
    unsigned short* us0 = (unsigned short*)&u0;
    unsigned short* us1 = (unsigned short*)&u1;
    #pragma unroll
    for (int i=0;i<8;++i) tile[c0+i][r] = us0[i];
    #pragma unroll
    for (int i=0;i<8;++i) tile[c0+8+i][r] = us1[i];
  }
  __syncthreads();
  {
    int n = t>>2, ks = (t&3)*16;
    *(uint4*)(dst + (long)(n0+n)*512 + k0 + ks)     = *(uint4*)&tile[n][ks];
    *(uint4*)(dst + (long)(n0+n)*512 + k0 + ks + 8) = *(uint4*)&tile[n][ks+8];
  }
}

// ---------------- QKV projection (bf16 MFMA, f32 inputs) ----------------
// q,k natural [token][512] bf16; v per-head-transposed [(b*8+h)*64+d][1024] bf16.
__global__ __launch_bounds__(256) void proj_mfma(
    const float* queries, const float* keys, const unsigned short* wt,
    const float* bq, const float* bk, const float* bv,
    unsigned short* q_bf, unsigned short* k_bf, unsigned short* vt_bf)
{
  const int mat = blockIdx.z;
  const float* A = (mat==0)? queries : keys;
  const unsigned short* Wt = wt + (long)mat*262144;
  const float* bias = (mat==0)?bq:(mat==1)?bk:bv;
  const int row0 = blockIdx.y*128, col0 = blockIdx.x*128;
  __shared__ unsigned short As[128][40];
  __shared__ unsigned short Ws[128][40];
  const int t = threadIdx.x;
  const int lane = t & 63, wid = t >> 6;
  const int ln = lane & 15, quad = lane >> 4;
  const int wy = wid >> 1, wx = wid & 1;
  f32x4 acc[4][4];
  #pragma unroll
  for (int i=0;i<4;++i){
    #pragma unroll
    for (int j=0;j<4;++j) acc[i][j] = (f32x4){0.f,0.f,0.f,0.f};
  }
  const int sr = t>>1, sk0 = (t&1)*16;
  for (int k0=0;k0<512;k0+=32){
    __syncthreads();
    {
      *(uint4*)&As[sr][sk0]   = pack8(A + (long)(row0+sr)*512 + k0 + sk0);
      *(uint4*)&As[sr][sk0+8] = pack8(A + (long)(row0+sr)*512 + k0 + sk0 + 8);
      *(uint4*)&Ws[sr][sk0]   = *(const uint4*)(Wt + (long)(col0+sr)*512 + k0 + sk0);
      *(uint4*)&Ws[sr][sk0+8] = *(const uint4*)(Wt + (long)(col0+sr)*512 + k0 + sk0 + 8);
    }
    __syncthreads();
    short8 a[4], b[4];
    #pragma unroll
    for (int mt=0;mt<4;++mt) a[mt] = *(const short8*)&As[wy*64+mt*16+ln][quad*8];
    #pragma unroll
    for (int nt=0;nt<4;++nt) b[nt] = *(const short8*)&Ws[wx*64+nt*16+ln][quad*8];
    #pragma unroll
    for (int mt=0;mt<4;++mt){
      #pragma unroll
      for (int nt=0;nt<4;++nt)
        acc[mt][nt] = __builtin_amdgcn_mfma_f32_16x16x32_bf16(a[mt], b[nt], acc[mt][nt], 0,0,0);
    }
  }
  float bias_v[4];
  #pragma unroll
  for (int nt=0;nt<4;++nt) bias_v[nt] = bias[col0 + wx*64 + nt*16 + ln];
  if (mat < 2){
    unsigned short* dst = (mat==0)? q_bf : k_bf;
    #pragma unroll
    for (int mt=0;mt<4;++mt){
      int row = row0 + wy*64 + mt*16 + quad*4;
      #pragma unroll
      for (int nt=0;nt<4;++nt){
        int col = col0 + wx*64 + nt*16 + ln;
        #pragma unroll
        for (int r=0;r<4;++r)
          dst[(long)(row+r)*512 + col] = f2b(acc[mt][nt][r] + bias_v[nt]);
      }
    }
  } else {
    #pragma unroll
    for (int mt=0;mt<4;++mt){
      int row = row0 + wy*64 + mt*16 + quad*4;   // token base, 4-aligned
      int bb = row >> 10, sk = row & 1023;
      #pragma unroll
      for (int nt=0;nt<4;++nt){
        int col = col0 + wx*64 + nt*16 + ln;
        int h = col >> 6, dd = col & 63;
        uint2 pk2; unsigned short* pp = (unsigned short*)&pk2;
        #pragma unroll
        for (int r=0;r<4;++r) pp[r] = f2b(acc[mt][nt][r] + bias_v[nt]);
        *(uint2*)(vt_bf + (((long)((bb*8+h)*64+dd)) << 10) + sk) = pk2;
      }
    }
  }
}

// ---------------- flash attention (bf16 MFMA, fixed-ref softmax) ----------------
// Block = (b,h) x 128-q tile, 512 threads / 8 waves, each wave a 16-q strip.
__global__ __launch_bounds__(512) void attn_mfma(
    const unsigned short* q_bf, const unsigned short* k_bf, const unsigned short* vt_bf,
    const float* pres_q, const float* pres_k, float* o1)
{
  const int bx = blockIdx.x;           // (b,h) fast: same-(b,h) tiles share an XCD
  const int b = bx >> 3, h = bx & 7;
  const int q0 = blockIdx.y * 128;
  const int t = threadIdx.x;
  const int lane = t & 63, wid = t >> 6, ln = lane & 15, quad = lane >> 4;
  __shared__ unsigned short Qs[128][72];  // [q][d]
  __shared__ unsigned short Ks[64][72];   // [key][d]
  __shared__ unsigned short Vt[64][72];   // [d][key]
  __shared__ unsigned short Ps[128][72];  // [q][key] bf16 exp-scores (wave-private rows)
  __shared__ float pq_s[128], pk_s[64];
  {
    int tok = t>>2, ds = (t&3)*16;
    const unsigned short* src = q_bf + (long)(b*1024 + q0 + tok)*512 + h*64 + ds;
    *(uint4*)&Qs[tok][ds]   = *(const uint4*)src;
    *(uint4*)&Qs[tok][ds+8] = *(const uint4*)(src+8);
  }
  if (t < 128) pq_s[t] = pres_q[b*1024 + q0 + t];
  __syncthreads();
  // hoisted Q frags + per-row pq*SCALE2
  short8 aq0 = *(const short8*)&Qs[wid*16+ln][quad*8];
  short8 aq1 = *(const short8*)&Qs[wid*16+ln][32+quad*8];
  float av[4];
  #pragma unroll
  for (int r=0;r<4;++r) av[r] = pq_s[wid*16 + quad*4 + r]*SCALE2;
  f32x4 oacc[4];
  #pragma unroll
  for (int dt=0;dt<4;++dt) oacc[dt] = (f32x4){0.f,0.f,0.f,0.f};
  float lsum[4] = {0.f,0.f,0.f,0.f};

  for (int k0=0;k0<1024;k0+=64){
    __syncthreads();                     // prev-iter Ks/Vt reads done
    {
      int tok = t>>3, ds = (t&7)*8;
      *(uint4*)&Ks[tok][ds] = *(const uint4*)(k_bf + (long)(b*1024 + k0 + tok)*512 + h*64 + ds);
      *(uint4*)&Vt[tok][ds] = *(const uint4*)(vt_bf + (((long)((b*8+h)*64 + tok)) << 10) + k0 + ds);
    }
    if (t < 64) pk_s[t] = pres_k[b*1024 + k0 + t];
    __syncthreads();
    // S = Q K^T : 16q x 64k per wave
    f32x4 s[4];
    #pragma unroll
    for (int kt=0;kt<4;++kt) s[kt] = (f32x4){0.f,0.f,0.f,0.f};
    #pragma unroll
    for (int kt=0;kt<4;++kt){
      short8 kb0 = *(const short8*)&Ks[kt*16+ln][quad*8];
      short8 kb1 = *(const short8*)&Ks[kt*16+ln][32+quad*8];
      s[kt] = __builtin_amdgcn_mfma_f32_16x16x32_bf16(aq0, kb0, s[kt], 0,0,0);
      s[kt] = __builtin_amdgcn_mfma_f32_16x16x32_bf16(aq1, kb1, s[kt], 0,0,0);
    }
    float pk4[4];
    #pragma unroll
    for (int kt=0;kt<4;++kt) pk4[kt] = pk_s[kt*16+ln];
    // fixed-ref softmax: e = exp2(raw*a + (a*C1 - 43)), a = pq*pk*SCALE2.
    // unmasked: exponent == raw*SCALE2 exactly; masked: 2^-43 (uniform for dead rows).
    #pragma unroll
    for (int r=0;r<4;++r){
      float sv[4];
      #pragma unroll
      for (int kt=0;kt<4;++kt){
        float a = av[r]*pk4[kt];
        float c = __builtin_fmaf(a, C1, -43.f);
        float x = __builtin_fmaf(s[kt][r], a, c);
        x = fminf(fmaxf(x, -100.f), 60.f);   // always-finite guard
        float e = __builtin_amdgcn_exp2f(x);
        lsum[r] += e;
        sv[kt] = e;
      }
      int prow = wid*16 + quad*4 + r;
      #pragma unroll
      for (int kt=0;kt<4;++kt) Ps[prow][kt*16+ln] = f2b(sv[kt]);
    }
    // O += P V : 16q x 64d per wave (Ps rows wave-private: no barrier needed)
    short8 ap0 = *(const short8*)&Ps[wid*16+ln][quad*8];
    short8 ap1 = *(const short8*)&Ps[wid*16+ln][32+quad*8];
    #pragma unroll
    for (int dt=0;dt<4;++dt){
      short8 vb0 = *(const short8*)&Vt[dt*16+ln][quad*8];
      short8 vb1 = *(const short8*)&Vt[dt*16+ln][32+quad*8];
      oacc[dt] = __builtin_amdgcn_mfma_f32_16x16x32_bf16(ap0, vb0, oacc[dt], 0,0,0);
      oacc[dt] = __builtin_amdgcn_mfma_f32_16x16x32_bf16(ap1, vb1, oacc[dt], 0,0,0);
    }
  }
  // epilogue: o = qh + (P V)/l ; l reduced once across the 16-lane crew
  #pragma unroll
  for (int r=0;r<4;++r){
    float l = lsum[r];
    #pragma unroll
    for (int msk=1; msk<16; msk<<=1) l += __shfl_xor(l, msk);
    float inv = 1.f / l;
    int ql = wid*16 + quad*4 + r;
    long base = (long)(b*1024 + q0 + ql)*512 + h*64;
    #pragma unroll
    for (int dt=0;dt<4;++dt)
      o1[base + dt*16 + ln] = bfu(Qs[ql][dt*16+ln]) + oacc[dt][r]*inv;
  }
}

// ---------------- layernorm (wave per row) ----------------
// mode 0: bf16 store to internal t_bf; mode 1: f32 float4 store to d_out
__global__ __launch_bounds__(256) void ln_kernel(
    const float* in, void* outp, int mode, const float* g, const float* bvec)
{
  const int row = blockIdx.x*4 + (threadIdx.x >> 6);
  const int lane = threadIdx.x & 63;
  const float* x = in + (long)row*512 + lane*8;
  float v[8];
  *(float4*)&v[0] = *(const float4*)x;
  *(float4*)&v[4] = *(const float4*)(x + 4);
  float sum = 0.f;
  #pragma unroll
  for (int c=0;c<8;++c) sum += v[c];
  #pragma unroll
  for (int msk=1; msk<64; msk<<=1) sum += __shfl_xor(sum, msk);
  float mu = sum * (1.f/512.f);
  float var = 0.f;
  #pragma unroll
  for (int c=0;c<8;++c){ v[c] -= mu; var += v[c]*v[c]; }
  #pragma unroll
  for (int msk=1; msk<64; msk<<=1) var += __shfl_xor(var, msk);
  float rs = rsqrtf(var*(1.f/512.f) + 1e-5f);
  float gv[8], bv[8];
  *(float4*)&gv[0] = *(const float4*)(g + lane*8);
  *(float4*)&gv[4] = *(const float4*)(g + lane*8 + 4);
  *(float4*)&bv[0] = *(const float4*)(bvec + lane*8);
  *(float4*)&bv[4] = *(const float4*)(bvec + lane*8 + 4);
  float y[8];
  #pragma unroll
  for (int c=0;c<8;++c) y[c] = v[c]*rs*gv[c] + bv[c];
  if (mode){
    float* dst = (float*)outp + (long)row*512 + lane*8;
    *(float4*)dst       = *(float4*)&y[0];
    *(float4*)(dst + 4) = *(float4*)&y[4];
  } else {
    uint4 out; unsigned short* os = (unsigned short*)&out;
    #pragma unroll
    for (int c=0;c<8;++c) os[c] = f2b(y[c]);
    *(uint4*)((unsigned short*)outp + (long)row*512 + lane*8) = out;
  }
}

// ---------------- out projection: u = t + relu(t @ Wo + bo) ----------------
__global__ __launch_bounds__(256) void out_mfma(
    const unsigned short* t_bf, const unsigned short* Wt, const float* bo,
    float* o1)
{
  const int row0 = blockIdx.y*128, col0 = blockIdx.x*128;
  __shared__ unsigned short As[128][40];
  __shared__ unsigned short Ws[128][40];
  const int t = threadIdx.x;
  const int lane = t & 63, wid = t >> 6;
  const int ln = lane & 15, quad = lane >> 4;
  const int wy = wid >> 1, wx = wid & 1;
  f32x4 acc[4][4];
  #pragma unroll
  for (int i=0;i<4;++i){
    #pragma unroll
    for (int j=0;j<4;++j) acc[i][j] = (f32x4){0.f,0.f,0.f,0.f};
  }
  const int sr = t>>1, sk0 = (t&1)*16;
  for (int k0=0;k0<512;k0+=32){
    __syncthreads();
    *(uint4*)&As[sr][sk0]   = *(const uint4*)(t_bf + (long)(row0+sr)*512 + k0 + sk0);
    *(uint4*)&As[sr][sk0+8] = *(const uint4*)(t_bf + (long)(row0+sr)*512 + k0 + sk0 + 8);
    *(uint4*)&Ws[sr][sk0]   = *(const uint4*)(Wt + (long)(col0+sr)*512 + k0 + sk0);
    *(uint4*)&Ws[sr][sk0+8] = *(const uint4*)(Wt + (long)(col0+sr)*512 + k0 + sk0 + 8);
    __syncthreads();
    short8 a[4], b[4];
    #pragma unroll
    for (int mt=0;mt<4;++mt) a[mt] = *(const short8*)&As[wy*64+mt*16+ln][quad*8];
    #pragma unroll
    for (int nt=0;nt<4;++nt) b[nt] = *(const short8*)&Ws[wx*64+nt*16+ln][quad*8];
    #pragma unroll
    for (int mt=0;mt<4;++mt){
      #pragma unroll
      for (int nt=0;nt<4;++nt)
        acc[mt][nt] = __builtin_amdgcn_mfma_f32_16x16x32_bf16(a[mt], b[nt], acc[mt][nt], 0,0,0);
    }
  }
  float bias_v[4];
  #pragma unroll
  for (int nt=0;nt<4;++nt) bias_v[nt] = bo[col0 + wx*64 + nt*16 + ln];
  #pragma unroll
  for (int mt=0;mt<4;++mt){
    int row = row0 + wy*64 + mt*16 + quad*4;
    #pragma unroll
    for (int nt=0;nt<4;++nt){
      int col = col0 + wx*64 + nt*16 + ln;
      #pragma unroll
      for (int r=0;r<4;++r){
        long idx = (long)(row+r)*512 + col;
        float u = acc[mt][nt][r] + bias_v[nt];
        u = fmaxf(u, 0.f);
        o1[idx] = bfu(t_bf[idx]) + u;
      }
    }
  }
}

extern "C" void kernel_launch(void* const* d_in, const int* in_sizes, int n_in,
                              void* d_out, int out_size, void* d_ws, size_t ws_size,
                              hipStream_t stream)
{
  // ws: q_bf | k_bf | vt_bf | t_bf (bf16, 8.4MB ea) | wt 2MB | o1 f32 16.8MB
  unsigned short* q_bf  = (unsigned short*)d_ws;
  unsigned short* k_bf  = q_bf  + 8192l*512;
  unsigned short* vt_bf = k_bf  + 8192l*512;
  unsigned short* t_bf  = vt_bf + 8192l*512;
  unsigned short* wt    = t_bf  + 8192l*512;
  float* o1 = (float*)(wt + 4l*512*512);

  hipLaunchKernelGGL(prep_w, dim3(8,8,4), dim3(256), 0, stream,
                     (const float*)d_in[5], (const float*)d_in[7],
                     (const float*)d_in[9], (const float*)d_in[11], wt);
  hipLaunchKernelGGL(proj_mfma, dim3(4,64,3), dim3(256), 0, stream,
                     (const float*)d_in[0], (const float*)d_in[1], wt,
                     (const float*)d_in[6], (const float*)d_in[8],
                     (const float*)d_in[10], q_bf, k_bf, vt_bf);
  hipLaunchKernelGGL(attn_mfma, dim3(64,8), dim3(512), 0, stream,
                     q_bf, k_bf, vt_bf,
                     (const float*)d_in[2], (const float*)d_in[3], o1);
  hipLaunchKernelGGL(ln_kernel, dim3(2048), dim3(256), 0, stream,
                     o1, (void*)t_bf, 0, (const float*)d_in[13], (const float*)d_in[14]);
  hipLaunchKernelGGL(out_mfma, dim3(4,64), dim3(256), 0, stream,
                     t_bf, wt + 3l*512*512, (const float*)d_in[12], o1);
  hipLaunchKernelGGL(ln_kernel, dim3(2048), dim3(256), 0, stream,
                     o1, d_out, 1, (const float*)d_in[15], (const float*)d_in[16]);
}

// Round 9
// 213.442 us; speedup vs baseline: 1.3608x; 1.0376x over previous
//
#include <hip/hip_runtime.h>

typedef __attribute__((ext_vector_type(8))) short short8;
typedef __attribute__((ext_vector_type(4))) float f32x4;

#define SCALE2 0.06375871571f   // (1/sqrt(512)) * log2(e)
#define C1     674.4237f        // 43 / SCALE2

__device__ __forceinline__ float bfu(unsigned short u){
  return __uint_as_float(((unsigned int)u) << 16);
}
__device__ __forceinline__ unsigned short f2b(float x){   // RNE
  unsigned int b = __float_as_uint(x);
  return (unsigned short)((b + 0x7fffu + ((b>>16)&1u)) >> 16);
}
// 8 contiguous f32 -> 8 bf16 packed in a uint4
__device__ __forceinline__ uint4 pack8(const float* f){
  float4 a = *(const float4*)f, b = *(const float4*)(f+4);
  uint4 r;
  r.x = (unsigned)f2b(a.x) | ((unsigned)f2b(a.y)<<16);
  r.y = (unsigned)f2b(a.z) | ((unsigned)f2b(a.w)<<16);
  r.z = (unsigned)f2b(b.x) | ((unsigned)f2b(b.y)<<16);
  r.w = (unsigned)f2b(b.z) | ((unsigned)f2b(b.w)<<16);
  return r;
}

// ---------------- input convert: queries+keys f32 -> bf16 ----------------
__global__ __launch_bounds__(256) void conv_bf(
    const float* q, const float* k, unsigned short* dst)
{
  long i = ((long)blockIdx.x*256 + threadIdx.x)*8;
  const float* src = (i < 4194304) ? q + i : k + (i - 4194304);
  *(uint4*)(dst + i) = pack8(src);
}

// ---------------- weight transpose: wt[n][k] = W[k][n] (f32 -> bf16) ----------------
__global__ __launch_bounds__(256) void prep_w(
    const float* Wq, const float* Wk, const float* Wv, const float* Wo,
    unsigned short* wt)
{
  const int m = blockIdx.z;
  const float* W = (m==0)?Wq:(m==1)?Wk:(m==2)?Wv:Wo;
  unsigned short* dst = wt + (long)m*262144;
  __shared__ unsigned short tile[64][72];
  const int t = threadIdx.x;
  const int n0 = blockIdx.x*64, k0 = blockIdx.y*64;
  {
    int r = t>>2, c0 = (t&3)*16;
    uint4 u0 = pack8(W + (long)(k0+r)*512 + n0 + c0);
    uint4 u1 = pack8(W + (long)(k0+r)*512 + n0 + c0 + 8);
    unsigned short* us0 = (unsigned short*)&u0;
    unsigned short* us1 = (unsigned short*)&u1;
    #pragma unroll
    for (int i=0;i<8;++i) tile[c0+i][r] = us0[i];
    #pragma unroll
    for (int i=0;i<8;++i) tile[c0+8+i][r] = us1[i];
  }
  __syncthreads();
  {
    int n = t>>2, ks = (t&3)*16;
    *(uint4*)(dst + (long)(n0+n)*512 + k0 + ks)     = *(uint4*)&tile[n][ks];
    *(uint4*)(dst + (long)(n0+n)*512 + k0 + ks + 8) = *(uint4*)&tile[n][ks+8];
  }
}

// ---------------- QKV projection (bf16 MFMA, dbuf LDS, 1 barrier/iter) ----------------
// q,k natural [token][512] bf16; v per-head-transposed [(b*8+h)*64+d][1024] bf16.
__global__ __launch_bounds__(256) void proj_mfma(
    const unsigned short* qin, const unsigned short* kin, const unsigned short* wt,
    const float* bq, const float* bk, const float* bv,
    unsigned short* q_bf, unsigned short* k_bf, unsigned short* vt_bf)
{
  const int mat = blockIdx.z;
  const unsigned short* A = (mat==0)? qin : kin;
  const unsigned short* Wt = wt + (long)mat*262144;
  const float* bias = (mat==0)?bq:(mat==1)?bk:bv;
  const int row0 = blockIdx.y*128, col0 = blockIdx.x*128;
  __shared__ unsigned short As[2][128][40];
  __shared__ unsigned short Ws[2][128][40];
  const int t = threadIdx.x;
  const int lane = t & 63, wid = t >> 6;
  const int ln = lane & 15, quad = lane >> 4;
  const int wy = wid >> 1, wx = wid & 1;
  f32x4 acc[4][4];
  #pragma unroll
  for (int i=0;i<4;++i){
    #pragma unroll
    for (int j=0;j<4;++j) acc[i][j] = (f32x4){0.f,0.f,0.f,0.f};
  }
  const int sr = t>>1, sk0 = (t&1)*16;
  const unsigned short* Arow = A  + (long)(row0+sr)*512 + sk0;
  const unsigned short* Wrow = Wt + (long)(col0+sr)*512 + sk0;
  uint4 a0 = *(const uint4*)(Arow);
  uint4 a1 = *(const uint4*)(Arow + 8);
  uint4 w0 = *(const uint4*)(Wrow);
  uint4 w1 = *(const uint4*)(Wrow + 8);
  *(uint4*)&As[0][sr][sk0]   = a0;
  *(uint4*)&As[0][sr][sk0+8] = a1;
  *(uint4*)&Ws[0][sr][sk0]   = w0;
  *(uint4*)&Ws[0][sr][sk0+8] = w1;
  __syncthreads();
  for (int it=0; it<16; ++it){
    const int cur = it & 1;
    if (it < 15){
      a0 = *(const uint4*)(Arow + (it+1)*32);
      a1 = *(const uint4*)(Arow + (it+1)*32 + 8);
      w0 = *(const uint4*)(Wrow + (it+1)*32);
      w1 = *(const uint4*)(Wrow + (it+1)*32 + 8);
    }
    short8 a[4], b[4];
    #pragma unroll
    for (int mt=0;mt<4;++mt) a[mt] = *(const short8*)&As[cur][wy*64+mt*16+ln][quad*8];
    #pragma unroll
    for (int nt=0;nt<4;++nt) b[nt] = *(const short8*)&Ws[cur][wx*64+nt*16+ln][quad*8];
    #pragma unroll
    for (int mt=0;mt<4;++mt){
      #pragma unroll
      for (int nt=0;nt<4;++nt)
        acc[mt][nt] = __builtin_amdgcn_mfma_f32_16x16x32_bf16(a[mt], b[nt], acc[mt][nt], 0,0,0);
    }
    if (it < 15){
      *(uint4*)&As[cur^1][sr][sk0]   = a0;
      *(uint4*)&As[cur^1][sr][sk0+8] = a1;
      *(uint4*)&Ws[cur^1][sr][sk0]   = w0;
      *(uint4*)&Ws[cur^1][sr][sk0+8] = w1;
    }
    __syncthreads();
  }
  float bias_v[4];
  #pragma unroll
  for (int nt=0;nt<4;++nt) bias_v[nt] = bias[col0 + wx*64 + nt*16 + ln];
  if (mat < 2){
    unsigned short* dst = (mat==0)? q_bf : k_bf;
    #pragma unroll
    for (int mt=0;mt<4;++mt){
      int row = row0 + wy*64 + mt*16 + quad*4;
      #pragma unroll
      for (int nt=0;nt<4;++nt){
        int col = col0 + wx*64 + nt*16 + ln;
        #pragma unroll
        for (int r=0;r<4;++r)
          dst[(long)(row+r)*512 + col] = f2b(acc[mt][nt][r] + bias_v[nt]);
      }
    }
  } else {
    #pragma unroll
    for (int mt=0;mt<4;++mt){
      int row = row0 + wy*64 + mt*16 + quad*4;   // token base, 4-aligned
      int bb = row >> 10, sk = row & 1023;
      #pragma unroll
      for (int nt=0;nt<4;++nt){
        int col = col0 + wx*64 + nt*16 + ln;
        int h = col >> 6, dd = col & 63;
        uint2 pk2; unsigned short* pp = (unsigned short*)&pk2;
        #pragma unroll
        for (int r=0;r<4;++r) pp[r] = f2b(acc[mt][nt][r] + bias_v[nt]);
        *(uint2*)(vt_bf + (((long)((bb*8+h)*64+dd)) << 10) + sk) = pk2;
      }
    }
  }
}

// ---------------- flash attention (bf16 MFMA, fixed-ref softmax) ----------------
// Block = (b,h) x 128-q tile, 512 threads / 8 waves, each wave a 16-q strip.
__global__ __launch_bounds__(512) void attn_mfma(
    const unsigned short* q_bf, const unsigned short* k_bf, const unsigned short* vt_bf,
    const float* pres_q, const float* pres_k, float* o1)
{
  const int bx = blockIdx.x;           // (b,h) fast: same-(b,h) tiles share an XCD
  const int b = bx >> 3, h = bx & 7;
  const int q0 = blockIdx.y * 128;
  const int t = threadIdx.x;
  const int lane = t & 63, wid = t >> 6, ln = lane & 15, quad = lane >> 4;
  __shared__ unsigned short Qs[128][72];  // [q][d]
  __shared__ unsigned short Ks[64][72];   // [key][d]
  __shared__ unsigned short Vt[64][72];   // [d][key]
  __shared__ unsigned short Ps[128][72];  // [q][key] bf16 exp-scores (wave-private rows)
  __shared__ float pq_s[128], pk_s[64];
  {
    int tok = t>>2, ds = (t&3)*16;
    const unsigned short* src = q_bf + (long)(b*1024 + q0 + tok)*512 + h*64 + ds;
    *(uint4*)&Qs[tok][ds]   = *(const uint4*)src;
    *(uint4*)&Qs[tok][ds+8] = *(const uint4*)(src+8);
  }
  if (t < 128) pq_s[t] = pres_q[b*1024 + q0 + t];
  __syncthreads();
  short8 aq0 = *(const short8*)&Qs[wid*16+ln][quad*8];
  short8 aq1 = *(const short8*)&Qs[wid*16+ln][32+quad*8];
  float av[4];
  #pragma unroll
  for (int r=0;r<4;++r) av[r] = pq_s[wid*16 + quad*4 + r]*SCALE2;
  f32x4 oacc[4];
  #pragma unroll
  for (int dt=0;dt<4;++dt) oacc[dt] = (f32x4){0.f,0.f,0.f,0.f};
  float lsum[4] = {0.f,0.f,0.f,0.f};

  for (int k0=0;k0<1024;k0+=64){
    __syncthreads();                     // prev-iter Ks/Vt reads done
    {
      int tok = t>>3, ds = (t&7)*8;
      *(uint4*)&Ks[tok][ds] = *(const uint4*)(k_bf + (long)(b*1024 + k0 + tok)*512 + h*64 + ds);
      *(uint4*)&Vt[tok][ds] = *(const uint4*)(vt_bf + (((long)((b*8+h)*64 + tok)) << 10) + k0 + ds);
    }
    if (t < 64) pk_s[t] = pres_k[b*1024 + k0 + t];
    __syncthreads();
    f32x4 s[4];
    #pragma unroll
    for (int kt=0;kt<4;++kt) s[kt] = (f32x4){0.f,0.f,0.f,0.f};
    #pragma unroll
    for (int kt=0;kt<4;++kt){
      short8 kb0 = *(const short8*)&Ks[kt*16+ln][quad*8];
      short8 kb1 = *(const short8*)&Ks[kt*16+ln][32+quad*8];
      s[kt] = __builtin_amdgcn_mfma_f32_16x16x32_bf16(aq0, kb0, s[kt], 0,0,0);
      s[kt] = __builtin_amdgcn_mfma_f32_16x16x32_bf16(aq1, kb1, s[kt], 0,0,0);
    }
    float pk4[4];
    #pragma unroll
    for (int kt=0;kt<4;++kt) pk4[kt] = pk_s[kt*16+ln];
    // fixed-ref softmax: e = exp2(raw*a + (a*C1 - 43)), a = pq*pk*SCALE2.
    #pragma unroll
    for (int r=0;r<4;++r){
      float sv[4];
      #pragma unroll
      for (int kt=0;kt<4;++kt){
        float a = av[r]*pk4[kt];
        float c = __builtin_fmaf(a, C1, -43.f);
        float x = __builtin_fmaf(s[kt][r], a, c);
        x = fminf(fmaxf(x, -100.f), 60.f);   // always-finite guard
        float e = __builtin_amdgcn_exp2f(x);
        lsum[r] += e;
        sv[kt] = e;
      }
      int prow = wid*16 + quad*4 + r;
      #pragma unroll
      for (int kt=0;kt<4;++kt) Ps[prow][kt*16+ln] = f2b(sv[kt]);
    }
    short8 ap0 = *(const short8*)&Ps[wid*16+ln][quad*8];
    short8 ap1 = *(const short8*)&Ps[wid*16+ln][32+quad*8];
    #pragma unroll
    for (int dt=0;dt<4;++dt){
      short8 vb0 = *(const short8*)&Vt[dt*16+ln][quad*8];
      short8 vb1 = *(const short8*)&Vt[dt*16+ln][32+quad*8];
      oacc[dt] = __builtin_amdgcn_mfma_f32_16x16x32_bf16(ap0, vb0, oacc[dt], 0,0,0);
      oacc[dt] = __builtin_amdgcn_mfma_f32_16x16x32_bf16(ap1, vb1, oacc[dt], 0,0,0);
    }
  }
  #pragma unroll
  for (int r=0;r<4;++r){
    float l = lsum[r];
    #pragma unroll
    for (int msk=1; msk<16; msk<<=1) l += __shfl_xor(l, msk);
    float inv = 1.f / l;
    int ql = wid*16 + quad*4 + r;
    long base = (long)(b*1024 + q0 + ql)*512 + h*64;
    #pragma unroll
    for (int dt=0;dt<4;++dt)
      o1[base + dt*16 + ln] = bfu(Qs[ql][dt*16+ln]) + oacc[dt][r]*inv;
  }
}

// ---------------- layernorm (wave per row) ----------------
// mode 0: bf16 store to internal t_bf; mode 1: f32 float4 store to d_out
__global__ __launch_bounds__(256) void ln_kernel(
    const float* in, void* outp, int mode, const float* g, const float* bvec)
{
  const int row = blockIdx.x*4 + (threadIdx.x >> 6);
  const int lane = threadIdx.x & 63;
  const float* x = in + (long)row*512 + lane*8;
  float v[8];
  *(float4*)&v[0] = *(const float4*)x;
  *(float4*)&v[4] = *(const float4*)(x + 4);
  float sum = 0.f;
  #pragma unroll
  for (int c=0;c<8;++c) sum += v[c];
  #pragma unroll
  for (int msk=1; msk<64; msk<<=1) sum += __shfl_xor(sum, msk);
  float mu = sum * (1.f/512.f);
  float var = 0.f;
  #pragma unroll
  for (int c=0;c<8;++c){ v[c] -= mu; var += v[c]*v[c]; }
  #pragma unroll
  for (int msk=1; msk<64; msk<<=1) var += __shfl_xor(var, msk);
  float rs = rsqrtf(var*(1.f/512.f) + 1e-5f);
  float gv[8], bv[8];
  *(float4*)&gv[0] = *(const float4*)(g + lane*8);
  *(float4*)&gv[4] = *(const float4*)(g + lane*8 + 4);
  *(float4*)&bv[0] = *(const float4*)(bvec + lane*8);
  *(float4*)&bv[4] = *(const float4*)(bvec + lane*8 + 4);
  float y[8];
  #pragma unroll
  for (int c=0;c<8;++c) y[c] = v[c]*rs*gv[c] + bv[c];
  if (mode){
    float* dst = (float*)outp + (long)row*512 + lane*8;
    *(float4*)dst       = *(float4*)&y[0];
    *(float4*)(dst + 4) = *(float4*)&y[4];
  } else {
    uint4 out; unsigned short* os = (unsigned short*)&out;
    #pragma unroll
    for (int c=0;c<8;++c) os[c] = f2b(y[c]);
    *(uint4*)((unsigned short*)outp + (long)row*512 + lane*8) = out;
  }
}

// ---------------- out projection: u = t + relu(t @ Wo + bo) ----------------
// 64x128 tiles (grid 4x128 = 512 blocks), dbuf LDS, 1 barrier/iter.
__global__ __launch_bounds__(256) void out_mfma(
    const unsigned short* t_bf, const unsigned short* Wt, const float* bo,
    float* o1)
{
  const int row0 = blockIdx.y*64, col0 = blockIdx.x*128;
  __shared__ unsigned short As[2][64][40];
  __shared__ unsigned short Ws[2][128][40];
  const int t = threadIdx.x;
  const int lane = t & 63, wid = t >> 6;
  const int ln = lane & 15, quad = lane >> 4;
  const int wy = wid >> 1, wx = wid & 1;   // wave: 32 rows x 64 cols
  f32x4 acc[2][4];
  #pragma unroll
  for (int i=0;i<2;++i){
    #pragma unroll
    for (int j=0;j<4;++j) acc[i][j] = (f32x4){0.f,0.f,0.f,0.f};
  }
  const int ar = t>>2, ac0 = (t&3)*8;
  const int wr = t>>1, wc0 = (t&1)*16;
  const unsigned short* Arow = t_bf + (long)(row0+ar)*512 + ac0;
  const unsigned short* Wrow = Wt   + (long)(col0+wr)*512 + wc0;
  uint4 a0 = *(const uint4*)(Arow);
  uint4 w0 = *(const uint4*)(Wrow);
  uint4 w1 = *(const uint4*)(Wrow + 8);
  *(uint4*)&As[0][ar][ac0] = a0;
  *(uint4*)&Ws[0][wr][wc0]   = w0;
  *(uint4*)&Ws[0][wr][wc0+8] = w1;
  __syncthreads();
  for (int it=0; it<16; ++it){
    const int cur = it & 1;
    if (it < 15){
      a0 = *(const uint4*)(Arow + (it+1)*32);
      w0 = *(const uint4*)(Wrow + (it+1)*32);
      w1 = *(const uint4*)(Wrow + (it+1)*32 + 8);
    }
    short8 a[2], b[4];
    #pragma unroll
    for (int mt=0;mt<2;++mt) a[mt] = *(const short8*)&As[cur][wy*32+mt*16+ln][quad*8];
    #pragma unroll
    for (int nt=0;nt<4;++nt) b[nt] = *(const short8*)&Ws[cur][wx*64+nt*16+ln][quad*8];
    #pragma unroll
    for (int mt=0;mt<2;++mt){
      #pragma unroll
      for (int nt=0;nt<4;++nt)
        acc[mt][nt] = __builtin_amdgcn_mfma_f32_16x16x32_bf16(a[mt], b[nt], acc[mt][nt], 0,0,0);
    }
    if (it < 15){
      *(uint4*)&As[cur^1][ar][ac0] = a0;
      *(uint4*)&Ws[cur^1][wr][wc0]   = w0;
      *(uint4*)&Ws[cur^1][wr][wc0+8] = w1;
    }
    __syncthreads();
  }
  float bias_v[4];
  #pragma unroll
  for (int nt=0;nt<4;++nt) bias_v[nt] = bo[col0 + wx*64 + nt*16 + ln];
  #pragma unroll
  for (int mt=0;mt<2;++mt){
    int row = row0 + wy*32 + mt*16 + quad*4;
    #pragma unroll
    for (int nt=0;nt<4;++nt){
      int col = col0 + wx*64 + nt*16 + ln;
      #pragma unroll
      for (int r=0;r<4;++r){
        long idx = (long)(row+r)*512 + col;
        float u = acc[mt][nt][r] + bias_v[nt];
        u = fmaxf(u, 0.f);
        o1[idx] = bfu(t_bf[idx]) + u;
      }
    }
  }
}

extern "C" void kernel_launch(void* const* d_in, const int* in_sizes, int n_in,
                              void* d_out, int out_size, void* d_ws, size_t ws_size,
                              hipStream_t stream)
{
  // ws: q_bf | k_bf | vt_bf | t_bf (bf16, 8.4MB ea) | wt 2MB | o1 f32 16.8MB
  // qin/kin (bf16 inputs) alias o1's space: consumed by proj before attn writes o1.
  unsigned short* q_bf  = (unsigned short*)d_ws;
  unsigned short* k_bf  = q_bf  + 8192l*512;
  unsigned short* vt_bf = k_bf  + 8192l*512;
  unsigned short* t_bf  = vt_bf + 8192l*512;
  unsigned short* wt    = t_bf  + 8192l*512;
  float* o1 = (float*)(wt + 4l*512*512);
  unsigned short* qin = (unsigned short*)o1;     // 4194304 bf16
  unsigned short* kin = qin + 4194304;           // 4194304 bf16

  hipLaunchKernelGGL(conv_bf, dim3(4096), dim3(256), 0, stream,
                     (const float*)d_in[0], (const float*)d_in[1], qin);
  hipLaunchKernelGGL(prep_w, dim3(8,8,4), dim3(256), 0, stream,
                     (const float*)d_in[5], (const float*)d_in[7],
                     (const float*)d_in[9], (const float*)d_in[11], wt);
  hipLaunchKernelGGL(proj_mfma, dim3(4,64,3), dim3(256), 0, stream,
                     qin, kin, wt,
                     (const float*)d_in[6], (const float*)d_in[8],
                     (const float*)d_in[10], q_bf, k_bf, vt_bf);
  hipLaunchKernelGGL(attn_mfma, dim3(64,8), dim3(512), 0, stream,
                     q_bf, k_bf, vt_bf,
                     (const float*)d_in[2], (const float*)d_in[3], o1);
  hipLaunchKernelGGL(ln_kernel, dim3(2048), dim3(256), 0, stream,
                     o1, (void*)t_bf, 0, (const float*)d_in[13], (const float*)d_in[14]);
  hipLaunchKernelGGL(out_mfma, dim3(4,128), dim3(256), 0, stream,
                     t_bf, wt + 3l*512*512, (const float*)d_in[12], o1);
  hipLaunchKernelGGL(ln_kernel, dim3(2048), dim3(256), 0, stream,
                     o1, d_out, 1, (const float*)d_in[15], (const float*)d_in[16]);
}

// Round 10
// 208.289 us; speedup vs baseline: 1.3944x; 1.0247x over previous
//
#include <hip/hip_runtime.h>

typedef __attribute__((ext_vector_type(8))) short short8;
typedef __attribute__((ext_vector_type(4))) float f32x4;

#define SCALE2 0.06375871571f   // (1/sqrt(512)) * log2(e)

__device__ __forceinline__ float bfu(unsigned short u){
  return __uint_as_float(((unsigned int)u) << 16);
}
__device__ __forceinline__ unsigned short f2b(float x){   // RNE
  unsigned int b = __float_as_uint(x);
  return (unsigned short)((b + 0x7fffu + ((b>>16)&1u)) >> 16);
}
// 8 contiguous f32 -> 8 bf16 packed in a uint4
__device__ __forceinline__ uint4 pack8(const float* f){
  float4 a = *(const float4*)f, b = *(const float4*)(f+4);
  uint4 r;
  r.x = (unsigned)f2b(a.x) | ((unsigned)f2b(a.y)<<16);
  r.y = (unsigned)f2b(a.z) | ((unsigned)f2b(a.w)<<16);
  r.z = (unsigned)f2b(b.x) | ((unsigned)f2b(b.y)<<16);
  r.w = (unsigned)f2b(b.z) | ((unsigned)f2b(b.w)<<16);
  return r;
}

// ---------------- fused input prep: weight transpose + q/k convert ----------------
// blocks 0..255: wt[n][k] = W[k][n] bf16; blocks 256..4351: q/k f32->bf16 copy.
__global__ __launch_bounds__(256) void prep_inputs(
    const float* Wq, const float* Wk, const float* Wv, const float* Wo,
    const float* q, const float* k, unsigned short* wt, unsigned short* qk_dst)
{
  const int id = blockIdx.x, t = threadIdx.x;
  if (id < 256){
    const int m = id >> 6;
    const float* W = (m==0)?Wq:(m==1)?Wk:(m==2)?Wv:Wo;
    unsigned short* dst = wt + (long)m*262144;
    __shared__ unsigned short tile[64][72];
    const int n0 = ((id>>3)&7)*64, k0 = (id&7)*64;
    {
      int r = t>>2, c0 = (t&3)*16;
      uint4 u0 = pack8(W + (long)(k0+r)*512 + n0 + c0);
      uint4 u1 = pack8(W + (long)(k0+r)*512 + n0 + c0 + 8);
      unsigned short* us0 = (unsigned short*)&u0;
      unsigned short* us1 = (unsigned short*)&u1;
      #pragma unroll
      for (int i=0;i<8;++i) tile[c0+i][r] = us0[i];
      #pragma unroll
      for (int i=0;i<8;++i) tile[c0+8+i][r] = us1[i];
    }
    __syncthreads();
    {
      int n = t>>2, ks = (t&3)*16;
      *(uint4*)(dst + (long)(n0+n)*512 + k0 + ks)     = *(uint4*)&tile[n][ks];
      *(uint4*)(dst + (long)(n0+n)*512 + k0 + ks + 8) = *(uint4*)&tile[n][ks+8];
    }
  } else {
    long i = ((long)(id-256)*256 + t)*8;
    const float* src = (i < 4194304) ? q + i : k + (i - 4194304);
    *(uint4*)(qk_dst + i) = pack8(src);
  }
}

// ---------------- QKV projection (bf16 MFMA, dbuf LDS, 1 barrier/iter) ----------------
__global__ __launch_bounds__(256) void proj_mfma(
    const unsigned short* qin, const unsigned short* kin, const unsigned short* wt,
    const float* bq, const float* bk, const float* bv,
    unsigned short* q_bf, unsigned short* k_bf, unsigned short* vt_bf)
{
  const int mat = blockIdx.z;
  const unsigned short* A = (mat==0)? qin : kin;
  const unsigned short* Wt = wt + (long)mat*262144;
  const float* bias = (mat==0)?bq:(mat==1)?bk:bv;
  const int row0 = blockIdx.y*128, col0 = blockIdx.x*128;
  __shared__ unsigned short As[2][128][40];
  __shared__ unsigned short Ws[2][128][40];
  const int t = threadIdx.x;
  const int lane = t & 63, wid = t >> 6;
  const int ln = lane & 15, quad = lane >> 4;
  const int wy = wid >> 1, wx = wid & 1;
  f32x4 acc[4][4];
  #pragma unroll
  for (int i=0;i<4;++i){
    #pragma unroll
    for (int j=0;j<4;++j) acc[i][j] = (f32x4){0.f,0.f,0.f,0.f};
  }
  const int sr = t>>1, sk0 = (t&1)*16;
  const unsigned short* Arow = A  + (long)(row0+sr)*512 + sk0;
  const unsigned short* Wrow = Wt + (long)(col0+sr)*512 + sk0;
  uint4 a0 = *(const uint4*)(Arow);
  uint4 a1 = *(const uint4*)(Arow + 8);
  uint4 w0 = *(const uint4*)(Wrow);
  uint4 w1 = *(const uint4*)(Wrow + 8);
  *(uint4*)&As[0][sr][sk0]   = a0;
  *(uint4*)&As[0][sr][sk0+8] = a1;
  *(uint4*)&Ws[0][sr][sk0]   = w0;
  *(uint4*)&Ws[0][sr][sk0+8] = w1;
  __syncthreads();
  for (int it=0; it<16; ++it){
    const int cur = it & 1;
    if (it < 15){
      a0 = *(const uint4*)(Arow + (it+1)*32);
      a1 = *(const uint4*)(Arow + (it+1)*32 + 8);
      w0 = *(const uint4*)(Wrow + (it+1)*32);
      w1 = *(const uint4*)(Wrow + (it+1)*32 + 8);
    }
    short8 a[4], b[4];
    #pragma unroll
    for (int mt=0;mt<4;++mt) a[mt] = *(const short8*)&As[cur][wy*64+mt*16+ln][quad*8];
    #pragma unroll
    for (int nt=0;nt<4;++nt) b[nt] = *(const short8*)&Ws[cur][wx*64+nt*16+ln][quad*8];
    #pragma unroll
    for (int mt=0;mt<4;++mt){
      #pragma unroll
      for (int nt=0;nt<4;++nt)
        acc[mt][nt] = __builtin_amdgcn_mfma_f32_16x16x32_bf16(a[mt], b[nt], acc[mt][nt], 0,0,0);
    }
    if (it < 15){
      *(uint4*)&As[cur^1][sr][sk0]   = a0;
      *(uint4*)&As[cur^1][sr][sk0+8] = a1;
      *(uint4*)&Ws[cur^1][sr][sk0]   = w0;
      *(uint4*)&Ws[cur^1][sr][sk0+8] = w1;
    }
    __syncthreads();
  }
  float bias_v[4];
  #pragma unroll
  for (int nt=0;nt<4;++nt) bias_v[nt] = bias[col0 + wx*64 + nt*16 + ln];
  if (mat < 2){
    unsigned short* dst = (mat==0)? q_bf : k_bf;
    #pragma unroll
    for (int mt=0;mt<4;++mt){
      int row = row0 + wy*64 + mt*16 + quad*4;
      #pragma unroll
      for (int nt=0;nt<4;++nt){
        int col = col0 + wx*64 + nt*16 + ln;
        #pragma unroll
        for (int r=0;r<4;++r)
          dst[(long)(row+r)*512 + col] = f2b(acc[mt][nt][r] + bias_v[nt]);
      }
    }
  } else {
    #pragma unroll
    for (int mt=0;mt<4;++mt){
      int row = row0 + wy*64 + mt*16 + quad*4;   // token base, 4-aligned
      int bb = row >> 10, sk = row & 1023;
      #pragma unroll
      for (int nt=0;nt<4;++nt){
        int col = col0 + wx*64 + nt*16 + ln;
        int h = col >> 6, dd = col & 63;
        uint2 pk2; unsigned short* pp = (unsigned short*)&pk2;
        #pragma unroll
        for (int r=0;r<4;++r) pp[r] = f2b(acc[mt][nt][r] + bias_v[nt]);
        *(uint2*)(vt_bf + (((long)((bb*8+h)*64+dd)) << 10) + sk) = pk2;
      }
    }
  }
}

// ---------------- flash attention (bf16 MFMA, dbuf K/V, lean softmax) ----------------
// Block = (b,h) x 128-q tile, 512 threads / 8 waves. QP buffer: Q staging -> Ps.
__global__ __launch_bounds__(512) void attn_mfma(
    const unsigned short* q_bf, const unsigned short* k_bf, const unsigned short* vt_bf,
    const float* pres_q, const float* pres_k, unsigned short* o_bf)
{
  const int bx = blockIdx.x;
  const int b = bx >> 3, h = bx & 7;
  const int q0 = blockIdx.y * 128;
  const int t = threadIdx.x;
  const int lane = t & 63, wid = t >> 6, ln = lane & 15, quad = lane >> 4;
  __shared__ unsigned short QP[128][72];   // Q staging, then Ps (wave-private rows)
  __shared__ unsigned short Ks[2][64][72];
  __shared__ unsigned short Vt[2][64][72];
  __shared__ float pq_s[128];
  __shared__ float pk_s[2][64];
  {
    int tok = t>>2, ds = (t&3)*16;
    const unsigned short* src = q_bf + (long)(b*1024 + q0 + tok)*512 + h*64 + ds;
    *(uint4*)&QP[tok][ds]   = *(const uint4*)src;
    *(uint4*)&QP[tok][ds+8] = *(const uint4*)(src+8);
  }
  {
    int tok = t>>3, ds = (t&7)*8;
    *(uint4*)&Ks[0][tok][ds] = *(const uint4*)(k_bf + (long)(b*1024 + tok)*512 + h*64 + ds);
    *(uint4*)&Vt[0][tok][ds] = *(const uint4*)(vt_bf + (((long)((b*8+h)*64 + tok)) << 10) + ds);
  }
  if (t < 128) pq_s[t] = pres_q[b*1024 + q0 + t];
  if (t < 64)  pk_s[0][t] = pres_k[b*1024 + t];
  __syncthreads();
  short8 aq0 = *(const short8*)&QP[wid*16+ln][quad*8];
  short8 aq1 = *(const short8*)&QP[wid*16+ln][32+quad*8];
  float av[4], mval[4];
  #pragma unroll
  for (int r=0;r<4;++r){
    av[r] = pq_s[wid*16 + quad*4 + r]*SCALE2;
    mval[r] = (av[r] == 0.f) ? 0.f : -43.f;   // masked-key exponent (ref-exact dead rows)
  }
  f32x4 oacc[4];
  #pragma unroll
  for (int dt=0;dt<4;++dt) oacc[dt] = (f32x4){0.f,0.f,0.f,0.f};
  float lsum[4] = {0.f,0.f,0.f,0.f};

  for (int it=0; it<16; ++it){
    const int cur = it & 1;
    const int k0n = (it+1)*64;
    uint4 pf_k, pf_v; float pf_p = 0.f;
    if (it < 15){
      int tok = t>>3, ds = (t&7)*8;
      pf_k = *(const uint4*)(k_bf + (long)(b*1024 + k0n + tok)*512 + h*64 + ds);
      pf_v = *(const uint4*)(vt_bf + (((long)((b*8+h)*64 + tok)) << 10) + k0n + ds);
      if (t < 64) pf_p = pres_k[b*1024 + k0n + t];
    }
    // S = Q K^T : 16q x 64k per wave
    f32x4 s[4];
    #pragma unroll
    for (int kt=0;kt<4;++kt) s[kt] = (f32x4){0.f,0.f,0.f,0.f};
    #pragma unroll
    for (int kt=0;kt<4;++kt){
      short8 kb0 = *(const short8*)&Ks[cur][kt*16+ln][quad*8];
      short8 kb1 = *(const short8*)&Ks[cur][kt*16+ln][32+quad*8];
      s[kt] = __builtin_amdgcn_mfma_f32_16x16x32_bf16(aq0, kb0, s[kt], 0,0,0);
      s[kt] = __builtin_amdgcn_mfma_f32_16x16x32_bf16(aq1, kb1, s[kt], 0,0,0);
    }
    float pk4[4];
    #pragma unroll
    for (int kt=0;kt<4;++kt) pk4[kt] = pk_s[cur][kt*16+ln];
    // x = pk ? s*av : mval  (pk in {0,1}): x = fma(pk, s*av - mval, mval)
    #pragma unroll
    for (int r=0;r<4;++r){
      #pragma unroll
      for (int kt=0;kt<4;++kt){
        float x0 = s[kt][r]*av[r];
        float x = __builtin_fmaf(pk4[kt], x0 - mval[r], mval[r]);
        float e = __builtin_amdgcn_exp2f(x);
        lsum[r] += e;
        // truncation bf16 store (folds to ds_write_b16_d16_hi)
        QP[wid*16+quad*4+r][kt*16+ln] = (unsigned short)(__float_as_uint(e) >> 16);
      }
    }
    // O += P V : 16q x 64d per wave (QP rows wave-private, LDS in-order per wave)
    short8 ap0 = *(const short8*)&QP[wid*16+ln][quad*8];
    short8 ap1 = *(const short8*)&QP[wid*16+ln][32+quad*8];
    #pragma unroll
    for (int dt=0;dt<4;++dt){
      short8 vb0 = *(const short8*)&Vt[cur][dt*16+ln][quad*8];
      short8 vb1 = *(const short8*)&Vt[cur][dt*16+ln][32+quad*8];
      oacc[dt] = __builtin_amdgcn_mfma_f32_16x16x32_bf16(ap0, vb0, oacc[dt], 0,0,0);
      oacc[dt] = __builtin_amdgcn_mfma_f32_16x16x32_bf16(ap1, vb1, oacc[dt], 0,0,0);
    }
    if (it < 15){
      int tok = t>>3, ds = (t&7)*8;
      *(uint4*)&Ks[cur^1][tok][ds] = pf_k;
      *(uint4*)&Vt[cur^1][tok][ds] = pf_v;
      if (t < 64) pk_s[cur^1][t] = pf_p;
    }
    __syncthreads();
  }
  // epilogue: o = qh + (P V)/l  (bf16 out); l reduced once over 16-lane crew
  #pragma unroll
  for (int r=0;r<4;++r){
    float l = lsum[r];
    #pragma unroll
    for (int msk=1; msk<16; msk<<=1) l += __shfl_xor(l, msk);
    float inv = 1.f / l;
    int ql = wid*16 + quad*4 + r;
    long base = (long)(b*1024 + q0 + ql)*512 + h*64;
    #pragma unroll
    for (int dt=0;dt<4;++dt){
      float qh = bfu(q_bf[base + dt*16 + ln]);
      o_bf[base + dt*16 + ln] = f2b(qh + oacc[dt][r]*inv);
    }
  }
}

// ---------------- layernorm (wave per row), bf16 input ----------------
// mode 0: bf16 store (t_bf); mode 1: f32 float4 store (d_out)
__global__ __launch_bounds__(256) void ln_kernel(
    const unsigned short* in, void* outp, int mode, const float* g, const float* bvec)
{
  const int row = blockIdx.x*4 + (threadIdx.x >> 6);
  const int lane = threadIdx.x & 63;
  uint4 raw = *(const uint4*)(in + (long)row*512 + lane*8);
  const unsigned short* rs16 = (const unsigned short*)&raw;
  float v[8];
  #pragma unroll
  for (int c=0;c<8;++c) v[c] = bfu(rs16[c]);
  float sum = 0.f;
  #pragma unroll
  for (int c=0;c<8;++c) sum += v[c];
  #pragma unroll
  for (int msk=1; msk<64; msk<<=1) sum += __shfl_xor(sum, msk);
  float mu = sum * (1.f/512.f);
  float var = 0.f;
  #pragma unroll
  for (int c=0;c<8;++c){ v[c] -= mu; var += v[c]*v[c]; }
  #pragma unroll
  for (int msk=1; msk<64; msk<<=1) var += __shfl_xor(var, msk);
  float rs = rsqrtf(var*(1.f/512.f) + 1e-5f);
  float gv[8], bv[8];
  *(float4*)&gv[0] = *(const float4*)(g + lane*8);
  *(float4*)&gv[4] = *(const float4*)(g + lane*8 + 4);
  *(float4*)&bv[0] = *(const float4*)(bvec + lane*8);
  *(float4*)&bv[4] = *(const float4*)(bvec + lane*8 + 4);
  float y[8];
  #pragma unroll
  for (int c=0;c<8;++c) y[c] = v[c]*rs*gv[c] + bv[c];
  if (mode){
    float* dst = (float*)outp + (long)row*512 + lane*8;
    *(float4*)dst       = *(float4*)&y[0];
    *(float4*)(dst + 4) = *(float4*)&y[4];
  } else {
    uint4 out; unsigned short* os = (unsigned short*)&out;
    #pragma unroll
    for (int c=0;c<8;++c) os[c] = f2b(y[c]);
    *(uint4*)((unsigned short*)outp + (long)row*512 + lane*8) = out;
  }
}

// ---------------- out projection: u = t + relu(t @ Wo + bo), bf16 out ----------------
__global__ __launch_bounds__(256) void out_mfma(
    const unsigned short* t_bf, const unsigned short* Wt, const float* bo,
    unsigned short* u_bf)
{
  const int row0 = blockIdx.y*64, col0 = blockIdx.x*128;
  __shared__ unsigned short As[2][64][40];
  __shared__ unsigned short Ws[2][128][40];
  const int t = threadIdx.x;
  const int lane = t & 63, wid = t >> 6;
  const int ln = lane & 15, quad = lane >> 4;
  const int wy = wid >> 1, wx = wid & 1;   // wave: 32 rows x 64 cols
  f32x4 acc[2][4];
  #pragma unroll
  for (int i=0;i<2;++i){
    #pragma unroll
    for (int j=0;j<4;++j) acc[i][j] = (f32x4){0.f,0.f,0.f,0.f};
  }
  const int ar = t>>2, ac0 = (t&3)*8;
  const int wr = t>>1, wc0 = (t&1)*16;
  const unsigned short* Arow = t_bf + (long)(row0+ar)*512 + ac0;
  const unsigned short* Wrow = Wt   + (long)(col0+wr)*512 + wc0;
  uint4 a0 = *(const uint4*)(Arow);
  uint4 w0 = *(const uint4*)(Wrow);
  uint4 w1 = *(const uint4*)(Wrow + 8);
  *(uint4*)&As[0][ar][ac0] = a0;
  *(uint4*)&Ws[0][wr][wc0]   = w0;
  *(uint4*)&Ws[0][wr][wc0+8] = w1;
  __syncthreads();
  for (int it=0; it<16; ++it){
    const int cur = it & 1;
    if (it < 15){
      a0 = *(const uint4*)(Arow + (it+1)*32);
      w0 = *(const uint4*)(Wrow + (it+1)*32);
      w1 = *(const uint4*)(Wrow + (it+1)*32 + 8);
    }
    short8 a[2], b[4];
    #pragma unroll
    for (int mt=0;mt<2;++mt) a[mt] = *(const short8*)&As[cur][wy*32+mt*16+ln][quad*8];
    #pragma unroll
    for (int nt=0;nt<4;++nt) b[nt] = *(const short8*)&Ws[cur][wx*64+nt*16+ln][quad*8];
    #pragma unroll
    for (int mt=0;mt<2;++mt){
      #pragma unroll
      for (int nt=0;nt<4;++nt)
        acc[mt][nt] = __builtin_amdgcn_mfma_f32_16x16x32_bf16(a[mt], b[nt], acc[mt][nt], 0,0,0);
    }
    if (it < 15){
      *(uint4*)&As[cur^1][ar][ac0] = a0;
      *(uint4*)&Ws[cur^1][wr][wc0]   = w0;
      *(uint4*)&Ws[cur^1][wr][wc0+8] = w1;
    }
    __syncthreads();
  }
  float bias_v[4];
  #pragma unroll
  for (int nt=0;nt<4;++nt) bias_v[nt] = bo[col0 + wx*64 + nt*16 + ln];
  #pragma unroll
  for (int mt=0;mt<2;++mt){
    int row = row0 + wy*32 + mt*16 + quad*4;
    #pragma unroll
    for (int nt=0;nt<4;++nt){
      int col = col0 + wx*64 + nt*16 + ln;
      #pragma unroll
      for (int r=0;r<4;++r){
        long idx = (long)(row+r)*512 + col;
        float u = acc[mt][nt][r] + bias_v[nt];
        u = fmaxf(u, 0.f);
        u_bf[idx] = f2b(bfu(t_bf[idx]) + u);
      }
    }
  }
}

extern "C" void kernel_launch(void* const* d_in, const int* in_sizes, int n_in,
                              void* d_out, int out_size, void* d_ws, size_t ws_size,
                              hipStream_t stream)
{
  // ws: q_bf | k_bf | vt_bf | t_bf (bf16 8.4MB ea) | wt 2MB | X 16.8MB
  // X first holds qin+kin (bf16 inputs); after proj consumes them,
  // o_bf aliases qin and u_bf aliases kin.
  unsigned short* q_bf  = (unsigned short*)d_ws;
  unsigned short* k_bf  = q_bf  + 8192l*512;
  unsigned short* vt_bf = k_bf  + 8192l*512;
  unsigned short* t_bf  = vt_bf + 8192l*512;
  unsigned short* wt    = t_bf  + 8192l*512;
  unsigned short* qin   = wt + 4l*512*512;
  unsigned short* kin   = qin + 4194304;
  unsigned short* o_bf  = qin;   // alias: valid after proj_mfma
  unsigned short* u_bf  = kin;   // alias: valid after proj_mfma

  hipLaunchKernelGGL(prep_inputs, dim3(4352), dim3(256), 0, stream,
                     (const float*)d_in[5], (const float*)d_in[7],
                     (const float*)d_in[9], (const float*)d_in[11],
                     (const float*)d_in[0], (const float*)d_in[1], wt, qin);
  hipLaunchKernelGGL(proj_mfma, dim3(4,64,3), dim3(256), 0, stream,
                     qin, kin, wt,
                     (const float*)d_in[6], (const float*)d_in[8],
                     (const float*)d_in[10], q_bf, k_bf, vt_bf);
  hipLaunchKernelGGL(attn_mfma, dim3(64,8), dim3(512), 0, stream,
                     q_bf, k_bf, vt_bf,
                     (const float*)d_in[2], (const float*)d_in[3], o_bf);
  hipLaunchKernelGGL(ln_kernel, dim3(2048), dim3(256), 0, stream,
                     o_bf, (void*)t_bf, 0, (const float*)d_in[13], (const float*)d_in[14]);
  hipLaunchKernelGGL(out_mfma, dim3(4,128), dim3(256), 0, stream,
                     t_bf, wt + 3l*512*512, (const float*)d_in[12], u_bf);
  hipLaunchKernelGGL(ln_kernel, dim3(2048), dim3(256), 0, stream,
                     u_bf, d_out, 1, (const float*)d_in[15], (const float*)d_in[16]);
}

// Round 11
// 207.236 us; speedup vs baseline: 1.4015x; 1.0051x over previous
//
#include <hip/hip_runtime.h>

typedef __attribute__((ext_vector_type(8))) short short8;
typedef __attribute__((ext_vector_type(4))) float f32x4;

#define SCALE2 0.06375871571f   // (1/sqrt(512)) * log2(e)

__device__ __forceinline__ float bfu(unsigned short u){
  return __uint_as_float(((unsigned int)u) << 16);
}
__device__ __forceinline__ unsigned short f2b(float x){   // RNE
  unsigned int b = __float_as_uint(x);
  return (unsigned short)((b + 0x7fffu + ((b>>16)&1u)) >> 16);
}
// 8 contiguous f32 -> 8 bf16 packed in a uint4
__device__ __forceinline__ uint4 pack8(const float* f){
  float4 a = *(const float4*)f, b = *(const float4*)(f+4);
  uint4 r;
  r.x = (unsigned)f2b(a.x) | ((unsigned)f2b(a.y)<<16);
  r.y = (unsigned)f2b(a.z) | ((unsigned)f2b(a.w)<<16);
  r.z = (unsigned)f2b(b.x) | ((unsigned)f2b(b.y)<<16);
  r.w = (unsigned)f2b(b.z) | ((unsigned)f2b(b.w)<<16);
  return r;
}

// ---------------- fused input prep: weight transpose + q/k convert ----------------
__global__ __launch_bounds__(256) void prep_inputs(
    const float* Wq, const float* Wk, const float* Wv, const float* Wo,
    const float* q, const float* k, unsigned short* wt, unsigned short* qk_dst)
{
  const int id = blockIdx.x, t = threadIdx.x;
  if (id < 256){
    const int m = id >> 6;
    const float* W = (m==0)?Wq:(m==1)?Wk:(m==2)?Wv:Wo;
    unsigned short* dst = wt + (long)m*262144;
    __shared__ unsigned short tile[64][72];
    const int n0 = ((id>>3)&7)*64, k0 = (id&7)*64;
    {
      int r = t>>2, c0 = (t&3)*16;
      uint4 u0 = pack8(W + (long)(k0+r)*512 + n0 + c0);
      uint4 u1 = pack8(W + (long)(k0+r)*512 + n0 + c0 + 8);
      unsigned short* us0 = (unsigned short*)&u0;
      unsigned short* us1 = (unsigned short*)&u1;
      #pragma unroll
      for (int i=0;i<8;++i) tile[c0+i][r] = us0[i];
      #pragma unroll
      for (int i=0;i<8;++i) tile[c0+8+i][r] = us1[i];
    }
    __syncthreads();
    {
      int n = t>>2, ks = (t&3)*16;
      *(uint4*)(dst + (long)(n0+n)*512 + k0 + ks)     = *(uint4*)&tile[n][ks];
      *(uint4*)(dst + (long)(n0+n)*512 + k0 + ks + 8) = *(uint4*)&tile[n][ks+8];
    }
  } else {
    long i = ((long)(id-256)*256 + t)*8;
    const float* src = (i < 4194304) ? q + i : k + (i - 4194304);
    *(uint4*)(qk_dst + i) = pack8(src);
  }
}

// ---------------- QKV projection (bf16 MFMA, dbuf LDS, 1 barrier/iter) ----------------
__global__ __launch_bounds__(256) void proj_mfma(
    const unsigned short* qin, const unsigned short* kin, const unsigned short* wt,
    const float* bq, const float* bk, const float* bv,
    unsigned short* q_bf, unsigned short* k_bf, unsigned short* vt_bf)
{
  const int mat = blockIdx.z;
  const unsigned short* A = (mat==0)? qin : kin;
  const unsigned short* Wt = wt + (long)mat*262144;
  const float* bias = (mat==0)?bq:(mat==1)?bk:bv;
  const int row0 = blockIdx.y*128, col0 = blockIdx.x*128;
  __shared__ unsigned short As[2][128][40];
  __shared__ unsigned short Ws[2][128][40];
  const int t = threadIdx.x;
  const int lane = t & 63, wid = t >> 6;
  const int ln = lane & 15, quad = lane >> 4;
  const int wy = wid >> 1, wx = wid & 1;
  f32x4 acc[4][4];
  #pragma unroll
  for (int i=0;i<4;++i){
    #pragma unroll
    for (int j=0;j<4;++j) acc[i][j] = (f32x4){0.f,0.f,0.f,0.f};
  }
  const int sr = t>>1, sk0 = (t&1)*16;
  const unsigned short* Arow = A  + (long)(row0+sr)*512 + sk0;
  const unsigned short* Wrow = Wt + (long)(col0+sr)*512 + sk0;
  uint4 a0 = *(const uint4*)(Arow);
  uint4 a1 = *(const uint4*)(Arow + 8);
  uint4 w0 = *(const uint4*)(Wrow);
  uint4 w1 = *(const uint4*)(Wrow + 8);
  *(uint4*)&As[0][sr][sk0]   = a0;
  *(uint4*)&As[0][sr][sk0+8] = a1;
  *(uint4*)&Ws[0][sr][sk0]   = w0;
  *(uint4*)&Ws[0][sr][sk0+8] = w1;
  __syncthreads();
  for (int it=0; it<16; ++it){
    const int cur = it & 1;
    if (it < 15){
      a0 = *(const uint4*)(Arow + (it+1)*32);
      a1 = *(const uint4*)(Arow + (it+1)*32 + 8);
      w0 = *(const uint4*)(Wrow + (it+1)*32);
      w1 = *(const uint4*)(Wrow + (it+1)*32 + 8);
    }
    short8 a[4], b[4];
    #pragma unroll
    for (int mt=0;mt<4;++mt) a[mt] = *(const short8*)&As[cur][wy*64+mt*16+ln][quad*8];
    #pragma unroll
    for (int nt=0;nt<4;++nt) b[nt] = *(const short8*)&Ws[cur][wx*64+nt*16+ln][quad*8];
    #pragma unroll
    for (int mt=0;mt<4;++mt){
      #pragma unroll
      for (int nt=0;nt<4;++nt)
        acc[mt][nt] = __builtin_amdgcn_mfma_f32_16x16x32_bf16(a[mt], b[nt], acc[mt][nt], 0,0,0);
    }
    if (it < 15){
      *(uint4*)&As[cur^1][sr][sk0]   = a0;
      *(uint4*)&As[cur^1][sr][sk0+8] = a1;
      *(uint4*)&Ws[cur^1][sr][sk0]   = w0;
      *(uint4*)&Ws[cur^1][sr][sk0+8] = w1;
    }
    __syncthreads();
  }
  float bias_v[4];
  #pragma unroll
  for (int nt=0;nt<4;++nt) bias_v[nt] = bias[col0 + wx*64 + nt*16 + ln];
  if (mat < 2){
    unsigned short* dst = (mat==0)? q_bf : k_bf;
    #pragma unroll
    for (int mt=0;mt<4;++mt){
      int row = row0 + wy*64 + mt*16 + quad*4;
      #pragma unroll
      for (int nt=0;nt<4;++nt){
        int col = col0 + wx*64 + nt*16 + ln;
        #pragma unroll
        for (int r=0;r<4;++r)
          dst[(long)(row+r)*512 + col] = f2b(acc[mt][nt][r] + bias_v[nt]);
      }
    }
  } else {
    #pragma unroll
    for (int mt=0;mt<4;++mt){
      int row = row0 + wy*64 + mt*16 + quad*4;   // token base, 4-aligned
      int bb = row >> 10, sk = row & 1023;
      #pragma unroll
      for (int nt=0;nt<4;++nt){
        int col = col0 + wx*64 + nt*16 + ln;
        int h = col >> 6, dd = col & 63;
        uint2 pk2; unsigned short* pp = (unsigned short*)&pk2;
        #pragma unroll
        for (int r=0;r<4;++r) pp[r] = f2b(acc[mt][nt][r] + bias_v[nt]);
        *(uint2*)(vt_bf + (((long)((bb*8+h)*64+dd)) << 10) + sk) = pk2;
      }
    }
  }
}

// ---------------- flash attention: 4 waves, 32 q-rows/wave (2 strips) ----------------
// K/V fragment loads amortize over 2 strips: 20 b128/wave/iter for 32 q-rows.
__global__ __launch_bounds__(256) void attn_mfma(
    const unsigned short* q_bf, const unsigned short* k_bf, const unsigned short* vt_bf,
    const float* pres_q, const float* pres_k, unsigned short* o_bf)
{
  const int bx = blockIdx.x;
  const int b = bx >> 3, h = bx & 7;
  const int q0 = blockIdx.y * 128;
  const int t = threadIdx.x;
  const int lane = t & 63, wid = t >> 6, ln = lane & 15, quad = lane >> 4;
  __shared__ unsigned short QP[128][72];   // Q staging, then Ps (wave-private rows)
  __shared__ unsigned short Ks[2][64][72];
  __shared__ unsigned short Vt[2][64][72];
  __shared__ float pq_s[128];
  __shared__ float pk_s[2][64];
  {
    int tok = t>>1, ds = (t&1)*32;       // 128 rows, 32 shorts each half
    const unsigned short* src = q_bf + (long)(b*1024 + q0 + tok)*512 + h*64 + ds;
    *(uint4*)&QP[tok][ds]    = *(const uint4*)src;
    *(uint4*)&QP[tok][ds+8]  = *(const uint4*)(src+8);
    *(uint4*)&QP[tok][ds+16] = *(const uint4*)(src+16);
    *(uint4*)&QP[tok][ds+24] = *(const uint4*)(src+24);
  }
  {
    int tok = t>>2, ds = (t&3)*16;
    const unsigned short* sk = k_bf + (long)(b*1024 + tok)*512 + h*64 + ds;
    *(uint4*)&Ks[0][tok][ds]   = *(const uint4*)sk;
    *(uint4*)&Ks[0][tok][ds+8] = *(const uint4*)(sk+8);
    const unsigned short* sv = vt_bf + (((long)((b*8+h)*64 + tok)) << 10) + ds;
    *(uint4*)&Vt[0][tok][ds]   = *(const uint4*)sv;
    *(uint4*)&Vt[0][tok][ds+8] = *(const uint4*)(sv+8);
  }
  if (t < 128) pq_s[t] = pres_q[b*1024 + q0 + t];
  if (t < 64)  pk_s[0][t] = pres_k[b*1024 + t];
  __syncthreads();
  // Q frags for both strips (rows wid*32 + s*16 + ln)
  short8 aq[2][2];
  float av[2][4], mval[2][4];
  #pragma unroll
  for (int s=0;s<2;++s){
    aq[s][0] = *(const short8*)&QP[wid*32+s*16+ln][quad*8];
    aq[s][1] = *(const short8*)&QP[wid*32+s*16+ln][32+quad*8];
    #pragma unroll
    for (int r=0;r<4;++r){
      av[s][r] = pq_s[wid*32 + s*16 + quad*4 + r]*SCALE2;
      mval[s][r] = (av[s][r] == 0.f) ? 0.f : -43.f;
    }
  }
  f32x4 oacc[2][4];
  float lsum[2][4];
  #pragma unroll
  for (int s=0;s<2;++s){
    #pragma unroll
    for (int i=0;i<4;++i){ oacc[s][i] = (f32x4){0.f,0.f,0.f,0.f}; lsum[s][i] = 0.f; }
  }

  for (int it=0; it<16; ++it){
    const int cur = it & 1;
    const int k0n = (it+1)*64;
    uint4 pf_k0, pf_k1, pf_v0, pf_v1; float pf_p = 0.f;
    if (it < 15){
      int tok = t>>2, ds = (t&3)*16;
      const unsigned short* sk = k_bf + (long)(b*1024 + k0n + tok)*512 + h*64 + ds;
      pf_k0 = *(const uint4*)sk;
      pf_k1 = *(const uint4*)(sk+8);
      const unsigned short* sv = vt_bf + (((long)((b*8+h)*64 + tok)) << 10) + k0n + ds;
      pf_v0 = *(const uint4*)sv;
      pf_v1 = *(const uint4*)(sv+8);
      if (t < 64) pf_p = pres_k[b*1024 + k0n + t];
    }
    // S = Q K^T : each kb fragment pair feeds BOTH strips
    f32x4 s[2][4];
    #pragma unroll
    for (int st=0;st<2;++st){
      #pragma unroll
      for (int kt=0;kt<4;++kt) s[st][kt] = (f32x4){0.f,0.f,0.f,0.f};
    }
    #pragma unroll
    for (int kt=0;kt<4;++kt){
      short8 kb0 = *(const short8*)&Ks[cur][kt*16+ln][quad*8];
      short8 kb1 = *(const short8*)&Ks[cur][kt*16+ln][32+quad*8];
      #pragma unroll
      for (int st=0;st<2;++st){
        s[st][kt] = __builtin_amdgcn_mfma_f32_16x16x32_bf16(aq[st][0], kb0, s[st][kt], 0,0,0);
        s[st][kt] = __builtin_amdgcn_mfma_f32_16x16x32_bf16(aq[st][1], kb1, s[st][kt], 0,0,0);
      }
    }
    float pk4[4];
    #pragma unroll
    for (int kt=0;kt<4;++kt) pk4[kt] = pk_s[cur][kt*16+ln];
    #pragma unroll
    for (int st=0;st<2;++st){
      #pragma unroll
      for (int r=0;r<4;++r){
        #pragma unroll
        for (int kt=0;kt<4;++kt){
          float x0 = s[st][kt][r]*av[st][r];
          float x = __builtin_fmaf(pk4[kt], x0 - mval[st][r], mval[st][r]);
          float e = __builtin_amdgcn_exp2f(x);
          lsum[st][r] += e;
          QP[wid*32+st*16+quad*4+r][kt*16+ln] = (unsigned short)(__float_as_uint(e) >> 16);
        }
      }
    }
    // O += P V : each vb fragment pair feeds BOTH strips
    short8 ap[2][2];
    #pragma unroll
    for (int st=0;st<2;++st){
      ap[st][0] = *(const short8*)&QP[wid*32+st*16+ln][quad*8];
      ap[st][1] = *(const short8*)&QP[wid*32+st*16+ln][32+quad*8];
    }
    #pragma unroll
    for (int dt=0;dt<4;++dt){
      short8 vb0 = *(const short8*)&Vt[cur][dt*16+ln][quad*8];
      short8 vb1 = *(const short8*)&Vt[cur][dt*16+ln][32+quad*8];
      #pragma unroll
      for (int st=0;st<2;++st){
        oacc[st][dt] = __builtin_amdgcn_mfma_f32_16x16x32_bf16(ap[st][0], vb0, oacc[st][dt], 0,0,0);
        oacc[st][dt] = __builtin_amdgcn_mfma_f32_16x16x32_bf16(ap[st][1], vb1, oacc[st][dt], 0,0,0);
      }
    }
    if (it < 15){
      int tok = t>>2, ds = (t&3)*16;
      *(uint4*)&Ks[cur^1][tok][ds]   = pf_k0;
      *(uint4*)&Ks[cur^1][tok][ds+8] = pf_k1;
      *(uint4*)&Vt[cur^1][tok][ds]   = pf_v0;
      *(uint4*)&Vt[cur^1][tok][ds+8] = pf_v1;
      if (t < 64) pk_s[cur^1][t] = pf_p;
    }
    __syncthreads();
  }
  // epilogue: o = qh + (P V)/l  (bf16 out)
  #pragma unroll
  for (int st=0;st<2;++st){
    #pragma unroll
    for (int r=0;r<4;++r){
      float l = lsum[st][r];
      #pragma unroll
      for (int msk=1; msk<16; msk<<=1) l += __shfl_xor(l, msk);
      float inv = 1.f / l;
      int ql = wid*32 + st*16 + quad*4 + r;
      long base = (long)(b*1024 + q0 + ql)*512 + h*64;
      #pragma unroll
      for (int dt=0;dt<4;++dt){
        float qh = bfu(q_bf[base + dt*16 + ln]);
        o_bf[base + dt*16 + ln] = f2b(qh + oacc[st][dt][r]*inv);
      }
    }
  }
}

// ---------------- layernorm (wave per row), bf16 input ----------------
__global__ __launch_bounds__(256) void ln_kernel(
    const unsigned short* in, void* outp, int mode, const float* g, const float* bvec)
{
  const int row = blockIdx.x*4 + (threadIdx.x >> 6);
  const int lane = threadIdx.x & 63;
  uint4 raw = *(const uint4*)(in + (long)row*512 + lane*8);
  const unsigned short* rs16 = (const unsigned short*)&raw;
  float v[8];
  #pragma unroll
  for (int c=0;c<8;++c) v[c] = bfu(rs16[c]);
  float sum = 0.f;
  #pragma unroll
  for (int c=0;c<8;++c) sum += v[c];
  #pragma unroll
  for (int msk=1; msk<64; msk<<=1) sum += __shfl_xor(sum, msk);
  float mu = sum * (1.f/512.f);
  float var = 0.f;
  #pragma unroll
  for (int c=0;c<8;++c){ v[c] -= mu; var += v[c]*v[c]; }
  #pragma unroll
  for (int msk=1; msk<64; msk<<=1) var += __shfl_xor(var, msk);
  float rs = rsqrtf(var*(1.f/512.f) + 1e-5f);
  float gv[8], bv[8];
  *(float4*)&gv[0] = *(const float4*)(g + lane*8);
  *(float4*)&gv[4] = *(const float4*)(g + lane*8 + 4);
  *(float4*)&bv[0] = *(const float4*)(bvec + lane*8);
  *(float4*)&bv[4] = *(const float4*)(bvec + lane*8 + 4);
  float y[8];
  #pragma unroll
  for (int c=0;c<8;++c) y[c] = v[c]*rs*gv[c] + bv[c];
  if (mode){
    float* dst = (float*)outp + (long)row*512 + lane*8;
    *(float4*)dst       = *(float4*)&y[0];
    *(float4*)(dst + 4) = *(float4*)&y[4];
  } else {
    uint4 out; unsigned short* os = (unsigned short*)&out;
    #pragma unroll
    for (int c=0;c<8;++c) os[c] = f2b(y[c]);
    *(uint4*)((unsigned short*)outp + (long)row*512 + lane*8) = out;
  }
}

// ---------------- out projection: u = t + relu(t @ Wo + bo), bf16 out ----------------
__global__ __launch_bounds__(256) void out_mfma(
    const unsigned short* t_bf, const unsigned short* Wt, const float* bo,
    unsigned short* u_bf)
{
  const int row0 = blockIdx.y*64, col0 = blockIdx.x*128;
  __shared__ unsigned short As[2][64][40];
  __shared__ unsigned short Ws[2][128][40];
  const int t = threadIdx.x;
  const int lane = t & 63, wid = t >> 6;
  const int ln = lane & 15, quad = lane >> 4;
  const int wy = wid >> 1, wx = wid & 1;   // wave: 32 rows x 64 cols
  f32x4 acc[2][4];
  #pragma unroll
  for (int i=0;i<2;++i){
    #pragma unroll
    for (int j=0;j<4;++j) acc[i][j] = (f32x4){0.f,0.f,0.f,0.f};
  }
  const int ar = t>>2, ac0 = (t&3)*8;
  const int wr = t>>1, wc0 = (t&1)*16;
  const unsigned short* Arow = t_bf + (long)(row0+ar)*512 + ac0;
  const unsigned short* Wrow = Wt   + (long)(col0+wr)*512 + wc0;
  uint4 a0 = *(const uint4*)(Arow);
  uint4 w0 = *(const uint4*)(Wrow);
  uint4 w1 = *(const uint4*)(Wrow + 8);
  *(uint4*)&As[0][ar][ac0] = a0;
  *(uint4*)&Ws[0][wr][wc0]   = w0;
  *(uint4*)&Ws[0][wr][wc0+8] = w1;
  __syncthreads();
  for (int it=0; it<16; ++it){
    const int cur = it & 1;
    if (it < 15){
      a0 = *(const uint4*)(Arow + (it+1)*32);
      w0 = *(const uint4*)(Wrow + (it+1)*32);
      w1 = *(const uint4*)(Wrow + (it+1)*32 + 8);
    }
    short8 a[2], b[4];
    #pragma unroll
    for (int mt=0;mt<2;++mt) a[mt] = *(const short8*)&As[cur][wy*32+mt*16+ln][quad*8];
    #pragma unroll
    for (int nt=0;nt<4;++nt) b[nt] = *(const short8*)&Ws[cur][wx*64+nt*16+ln][quad*8];
    #pragma unroll
    for (int mt=0;mt<2;++mt){
      #pragma unroll
      for (int nt=0;nt<4;++nt)
        acc[mt][nt] = __builtin_amdgcn_mfma_f32_16x16x32_bf16(a[mt], b[nt], acc[mt][nt], 0,0,0);
    }
    if (it < 15){
      *(uint4*)&As[cur^1][ar][ac0] = a0;
      *(uint4*)&Ws[cur^1][wr][wc0]   = w0;
      *(uint4*)&Ws[cur^1][wr][wc0+8] = w1;
    }
    __syncthreads();
  }
  float bias_v[4];
  #pragma unroll
  for (int nt=0;nt<4;++nt) bias_v[nt] = bo[col0 + wx*64 + nt*16 + ln];
  #pragma unroll
  for (int mt=0;mt<2;++mt){
    int row = row0 + wy*32 + mt*16 + quad*4;
    #pragma unroll
    for (int nt=0;nt<4;++nt){
      int col = col0 + wx*64 + nt*16 + ln;
      #pragma unroll
      for (int r=0;r<4;++r){
        long idx = (long)(row+r)*512 + col;
        float u = acc[mt][nt][r] + bias_v[nt];
        u = fmaxf(u, 0.f);
        u_bf[idx] = f2b(bfu(t_bf[idx]) + u);
      }
    }
  }
}

extern "C" void kernel_launch(void* const* d_in, const int* in_sizes, int n_in,
                              void* d_out, int out_size, void* d_ws, size_t ws_size,
                              hipStream_t stream)
{
  unsigned short* q_bf  = (unsigned short*)d_ws;
  unsigned short* k_bf  = q_bf  + 8192l*512;
  unsigned short* vt_bf = k_bf  + 8192l*512;
  unsigned short* t_bf  = vt_bf + 8192l*512;
  unsigned short* wt    = t_bf  + 8192l*512;
  unsigned short* qin   = wt + 4l*512*512;
  unsigned short* kin   = qin + 4194304;
  unsigned short* o_bf  = qin;   // alias: valid after proj_mfma
  unsigned short* u_bf  = kin;   // alias: valid after proj_mfma

  hipLaunchKernelGGL(prep_inputs, dim3(4352), dim3(256), 0, stream,
                     (const float*)d_in[5], (const float*)d_in[7],
                     (const float*)d_in[9], (const float*)d_in[11],
                     (const float*)d_in[0], (const float*)d_in[1], wt, qin);
  hipLaunchKernelGGL(proj_mfma, dim3(4,64,3), dim3(256), 0, stream,
                     qin, kin, wt,
                     (const float*)d_in[6], (const float*)d_in[8],
                     (const float*)d_in[10], q_bf, k_bf, vt_bf);
  hipLaunchKernelGGL(attn_mfma, dim3(64,8), dim3(256), 0, stream,
                     q_bf, k_bf, vt_bf,
                     (const float*)d_in[2], (const float*)d_in[3], o_bf);
  hipLaunchKernelGGL(ln_kernel, dim3(2048), dim3(256), 0, stream,
                     o_bf, (void*)t_bf, 0, (const float*)d_in[13], (const float*)d_in[14]);
  hipLaunchKernelGGL(out_mfma, dim3(4,128), dim3(256), 0, stream,
                     t_bf, wt + 3l*512*512, (const float*)d_in[12], u_bf);
  hipLaunchKernelGGL(ln_kernel, dim3(2048), dim3(256), 0, stream,
                     u_bf, d_out, 1, (const float*)d_in[15], (const float*)d_in[16]);
}